// Round 4
// baseline (341.219 us; speedup 1.0000x reference)
//
#include <hip/hip_runtime.h>
#include <hip/hip_bf16.h>
#include <hip/hip_fp16.h>

#define DIM 768
#define SLEN 4096
#define BATCH 4
#define NTILES 528   // 128-granular causal tiles per batch (PV/softmax layout)
#define NT256 136    // 256-granular causal tiles per batch (qk grid)

typedef __attribute__((ext_vector_type(8))) short short8;
typedef __attribute__((ext_vector_type(4))) short short4v;
typedef __attribute__((ext_vector_type(4))) float f32x4;
typedef __attribute__((ext_vector_type(8))) _Float16 f16x8;

typedef __attribute__((address_space(1))) void gvoid;
typedef __attribute__((address_space(3))) void lvoid;

__device__ __forceinline__ void gl_lds16(const void* g, void* l) {
  __builtin_amdgcn_global_load_lds((gvoid*)g, (lvoid*)l, 16, 0, 0);
}

__device__ __forceinline__ unsigned short f2h(float x) {
  union { _Float16 h; unsigned short u; } c; c.h = (_Float16)x; return c.u;
}
__device__ __forceinline__ float h2f(unsigned short u) {
  union { _Float16 h; unsigned short u; } c; c.u = u; return (float)c.h;
}

union V8 { short8 v; unsigned short u[8]; };

// ---------------- kernel 1: x fp32 -> fp16 ----------------
__global__ __launch_bounds__(256) void convert_x_kernel(
    const float* __restrict__ x, unsigned short* __restrict__ xb) {
  size_t i = ((size_t)blockIdx.x * 256 + threadIdx.x) * 8;
  f32x4 a = *(const f32x4*)(x + i);
  f32x4 b = *(const f32x4*)(x + i + 4);
  V8 o;
#pragma unroll
  for (int j = 0; j < 4; ++j) { o.u[j] = f2h(a[j]); o.u[4 + j] = f2h(b[j]); }
  *(short8*)(xb + i) = o.v;
}

// ---------------- kernel 2: W [k][n] fp32 -> Wt [n][k] fp16 ----------------
__global__ __launch_bounds__(256) void transpose_w_kernel(
    const float* __restrict__ Wq, const float* __restrict__ Wk,
    const float* __restrict__ Wv, unsigned short* __restrict__ Wt) {
  __shared__ float Tl[32][33];
  const float* Wi = blockIdx.z == 0 ? Wq : (blockIdx.z == 1 ? Wk : Wv);
  unsigned short* Wo = Wt + (size_t)blockIdx.z * DIM * DIM;
  int k0 = blockIdx.x * 32, n0 = blockIdx.y * 32;
  int t = threadIdx.x;
  int r = t >> 3, c4 = (t & 7) * 4;
  f32x4 v = *(const f32x4*)(Wi + (size_t)(k0 + r) * DIM + n0 + c4);
#pragma unroll
  for (int j = 0; j < 4; ++j) Tl[r][c4 + j] = v[j];
  __syncthreads();
  short4v ov;
#pragma unroll
  for (int j = 0; j < 4; ++j) ov[j] = (short)f2h(Tl[c4 + j][r]);
  *(short4v*)(Wo + (size_t)(n0 + r) * DIM + k0 + c4) = ov;
}

// ============ 256x256 8-phase GEMM (T2 swizzle + T3/T4 counted vmcnt + T5) ============
// C[m][n] = sum_k A[m][k] * B[n][k], both ld=DIM, K=768 (12 tiles of BK=64).
// MODE 0: qkv (z picks B-matrix / output, plain row-major C).
// MODE 1: qk causal 256-tiles; C scattered into packed-128 S layout.
// LDS: A buf0 @0, A buf1 @32768, B buf0 @65536, B buf1 @98304; each buf =
// 2 halves x 16384 B (128 rows x 64 f16). 16B chunk c of row r at slot
// c ^ (r&7), staged by inverse-swizzling the GLOBAL source chunk
// (gl_lds writes linearly at lane*16).
// SYNC RULE (round-3 post-mortem): vmcnt(N) only covers the waiting wave's
// own loads; a s_barrier must sit between the wait and any wave's ds_read
// of the staged tile. Waits: end of P0 (guards A1(t) read in P1) and end
// of P3 (guards A0/B0/B1(t+1) read in next P0). Prologue: vmcnt(4)+barrier.

#define STAGE(src, row0, kb, ldsoff)                                              \
  {                                                                               \
    gl_lds16((src) + (size_t)((row0) + rA) * DIM + (kb) + cA,                     \
             ldsb + (ldsoff) + t * 16);                                           \
    gl_lds16((src) + (size_t)((row0) + 64 + rA) * DIM + (kb) + cA,                \
             ldsb + (ldsoff) + 8192 + t * 16);                                    \
  }

#define QPHASE(MH, CHB, STG, VMW)                                                 \
  {                                                                               \
    f16x8 afr[4];                                                                 \
    _Pragma("unroll") for (int j = 0; j < 4; ++j)                                 \
        afr[j] = __builtin_bit_cast(f16x8, *(const short8*)(ldsb + aB +           \
                 (MH) * 16384 + (j * 32 + arow) * 128 + (CHB)));                  \
    if ((MH) == 0) {                                                              \
      _Pragma("unroll") for (int n = 0; n < 4; ++n)                               \
          bfr[n] = __builtin_bit_cast(f16x8, *(const short8*)(ldsb + bB +         \
                   bh * 16384 + (brow + n * 16) * 128 + (CHB)));                  \
    }                                                                             \
    STG;                                                                          \
    VMW;                                                                          \
    asm volatile("s_barrier" ::: "memory");                                       \
    asm volatile("s_waitcnt lgkmcnt(0)" ::: "memory");                            \
    __builtin_amdgcn_sched_barrier(0);                                            \
    __builtin_amdgcn_s_setprio(1);                                                \
    _Pragma("unroll") for (int j = 0; j < 4; ++j)                                 \
      _Pragma("unroll") for (int n = 0; n < 4; ++n)                               \
        acc[(MH) * 4 + j][n] = __builtin_amdgcn_mfma_f32_16x16x32_f16(            \
            afr[j], bfr[n], acc[(MH) * 4 + j][n], 0, 0, 0);                       \
    __builtin_amdgcn_s_setprio(0);                                                \
    __builtin_amdgcn_sched_barrier(0);                                            \
    asm volatile("s_barrier" ::: "memory");                                       \
  }

template <int MODE>
__global__ __launch_bounds__(512, 2) void gemm8_kernel(
    const unsigned short* __restrict__ Ag, const unsigned short* __restrict__ Bg,
    unsigned short* __restrict__ o0, unsigned short* __restrict__ o1,
    unsigned short* __restrict__ o2, size_t stAB, size_t stS) {
  __shared__ __align__(16) unsigned short lds[65536];  // 128 KiB
  char* ldsb = (char*)lds;
  const int t = threadIdx.x;
  const int lane = t & 63, w = t >> 6;
  const int l15 = lane & 15, lg = lane >> 4;
  const int wr = w >> 2, wc = w & 3;

  int m0, n0, qt = 0, kt = 0;
  const unsigned short *A, *B;
  unsigned short* Co = nullptr;
  unsigned short* Sb = nullptr;
  if (MODE == 0) {
    m0 = blockIdx.x * 256; n0 = blockIdx.y * 256;
    A = Ag; B = Bg + (size_t)blockIdx.z * DIM * DIM;
    Co = blockIdx.z == 0 ? o0 : (blockIdx.z == 1 ? o1 : o2);
  } else {
    const int i = blockIdx.x, b = blockIdx.y;
    qt = (int)((sqrtf(8.f * i + 1.f) - 1.f) * 0.5f);
    while ((qt + 1) * (qt + 2) / 2 <= i) ++qt;
    while (qt * (qt + 1) / 2 > i) --qt;
    kt = i - qt * (qt + 1) / 2;
    m0 = qt * 256; n0 = kt * 256;
    A = Ag + (size_t)b * stAB; B = Bg + (size_t)b * stAB;
    Sb = o0 + (size_t)b * stS;
  }

  // staging per-thread constants (inverse-swizzled global chunk)
  const int rA = t >> 3;
  const int cA = (((t & 7) ^ ((t >> 3) & 7)) << 3);  // element offset = chunk*8
  // ds_read swizzled chunk byte offset for ks=0 (ks=1 is ^64)
  const int ch0 = ((lg ^ (l15 & 7)) << 4);
  const int arow = wr * 16 + l15;        // A frag row within half (add j*32)
  const int bh = wc >> 1;                // B half
  const int brow = (wc & 1) * 64 + l15;  // B frag row within half (add n*16)

  f32x4 acc[8][4];
#pragma unroll
  for (int f = 0; f < 8; ++f)
#pragma unroll
    for (int n = 0; n < 4; ++n) acc[f][n] = f32x4{0.f, 0.f, 0.f, 0.f};

  // prologue: A0(0), B0(0), B1(0), A1(0), A0(1)  (oldest -> newest)
  STAGE(A, m0, 0, 0);
  STAGE(B, n0, 0, 65536);
  STAGE(B, n0 + 128, 0, 65536 + 16384);
  STAGE(A, m0 + 128, 0, 16384);
  STAGE(A, m0, 64, 32768);
  asm volatile("s_waitcnt vmcnt(4)" ::: "memory");  // own A0(0),B0(0),B1(0) landed
  asm volatile("s_barrier" ::: "memory");           // ... for ALL waves

  for (int tt = 0; tt < 12; ++tt) {
    const int bt = tt & 1;
    const int aB = bt * 32768;
    const int bB = 65536 + bt * 32768;
    const int aN = (1 - bt) * 32768;
    const int bN = 65536 + (1 - bt) * 32768;
    const int kb1 = (tt + 1 < 12 ? tt + 1 : 11) * 64;
    const int kb2 = (tt + 2 < 12 ? tt + 2 : 11) * 64;
    f16x8 bfr[4];
    QPHASE(0, ch0, STAGE(B, n0, kb1, bN),
           asm volatile("s_waitcnt vmcnt(4)" ::: "memory"));  // guards A1(t) for P1
    QPHASE(1, ch0, STAGE(B, n0 + 128, kb1, bN + 16384), (void)0);
    QPHASE(0, ch0 ^ 64, STAGE(A, m0 + 128, kb1, aN + 16384), (void)0);
    QPHASE(1, ch0 ^ 64, STAGE(A, m0, kb2, aB),
           asm volatile("s_waitcnt vmcnt(4)" ::: "memory"));  // guards t+1's P0 reads
  }
  asm volatile("s_waitcnt vmcnt(0)" ::: "memory");  // drain before LDS dealloc

  if (MODE == 0) {
#pragma unroll
    for (int f = 0; f < 8; ++f) {
      const int row = m0 + f * 32 + wr * 16 + lg * 4;
#pragma unroll
      for (int n = 0; n < 4; ++n) {
        const int col = n0 + wc * 64 + n * 16 + l15;
#pragma unroll
        for (int ii = 0; ii < 4; ++ii)
          Co[(size_t)(row + ii) * DIM + col] = f2h(acc[f][n][ii]);
      }
    }
  } else {
#pragma unroll
    for (int f = 0; f < 8; ++f) {
      const int rl = (f * 32 + wr * 16 + lg * 4) & 127;
      const int Q128 = qt * 2 + (f >= 4 ? 1 : 0);
      const int K128 = kt * 2 + (wc >> 1);
      if (K128 > Q128) continue;  // above-diagonal 128-quadrant (diag tiles)
      const size_t tb = (size_t)(Q128 * (Q128 + 1) / 2 + K128) * 16384;
#pragma unroll
      for (int n = 0; n < 4; ++n) {
        const int cl = ((wc & 1) * 64 + n * 16 + l15);
#pragma unroll
        for (int ii = 0; ii < 4; ++ii)
          Sb[tb + (size_t)(rl + ii) * 128 + cl] = f2h(acc[f][n][ii]);
      }
    }
  }
}

// ---------------- Vn [b*s][e] -> Vt [b][e][s] (64x64 LDS tiles) ----------------
__global__ __launch_bounds__(256) void transpose_v_kernel(
    const unsigned short* __restrict__ Vn, unsigned short* __restrict__ Vt) {
  __shared__ unsigned short T[64][72];
  const int s0 = blockIdx.x * 64, e0 = blockIdx.y * 64;
  const size_t bo = (size_t)blockIdx.z * SLEN * DIM;
  const int t = threadIdx.x;
  const int r = t >> 2, c = (t & 3) * 16;
  V8 v0, v1;
  v0.v = *(const short8*)(Vn + bo + (size_t)(s0 + r) * DIM + e0 + c);
  v1.v = *(const short8*)(Vn + bo + (size_t)(s0 + r) * DIM + e0 + c + 8);
#pragma unroll
  for (int j = 0; j < 8; ++j) { T[r][c + j] = v0.u[j]; T[r][c + 8 + j] = v1.u[j]; }
  __syncthreads();
  unsigned short* Ob = Vt + (size_t)blockIdx.z * DIM * SLEN;
  V8 o0, o1;
#pragma unroll
  for (int j = 0; j < 8; ++j) { o0.u[j] = T[c + j][r]; o1.u[j] = T[c + 8 + j][r]; }
  *(short8*)(Ob + (size_t)(e0 + r) * SLEN + s0 + c) = o0.v;
  *(short8*)(Ob + (size_t)(e0 + r) * SLEN + s0 + c + 8) = o1.v;
}

// ---------------- fallback V GEMM (128x128, writes Vt directly) ----------------
__global__ __launch_bounds__(256) void gemm_v128_kernel(
    const unsigned short* __restrict__ xb, const unsigned short* __restrict__ wt,
    unsigned short* __restrict__ Vt) {
  __shared__ __align__(16) unsigned short lds[128 * 136];
  unsigned short* As = lds;
  unsigned short* Bs = lds + 4096;
  const int t = threadIdx.x, lane = t & 63, w = t >> 6;
  const int l15 = lane & 15, lg = lane >> 4;
  const int wm = w >> 1, wn = w & 1;
  const int m0 = blockIdx.x * 128, n0 = blockIdx.y * 128;
  const unsigned short* B = wt + (size_t)2 * DIM * DIM;
  f32x4 acc[4][4];
#pragma unroll
  for (int a = 0; a < 4; ++a)
#pragma unroll
    for (int b2 = 0; b2 < 4; ++b2) acc[a][b2] = f32x4{0.f, 0.f, 0.f, 0.f};
  const int c0 = t, c1 = t + 256;
  const int r0 = c0 >> 2, k80 = (c0 & 3) * 8;
  const int r1 = c1 >> 2, k81 = (c1 & 3) * 8;
  for (int kb = 0; kb < DIM; kb += 32) {
    __syncthreads();
    gl_lds16(xb + (size_t)(m0 + r0) * DIM + kb + k80, As + (size_t)c0 * 8);
    gl_lds16(xb + (size_t)(m0 + r1) * DIM + kb + k81, As + (size_t)c1 * 8);
    gl_lds16(B + (size_t)(n0 + r0) * DIM + kb + k80, Bs + (size_t)c0 * 8);
    gl_lds16(B + (size_t)(n0 + r1) * DIM + kb + k81, Bs + (size_t)c1 * 8);
    __syncthreads();
    f16x8 a[4], bf[4];
#pragma unroll
    for (int mi = 0; mi < 4; ++mi)
      a[mi] = __builtin_bit_cast(f16x8, *(const short8*)(As + (wm * 64 + mi * 16 + l15) * 32 + lg * 8));
#pragma unroll
    for (int ni = 0; ni < 4; ++ni)
      bf[ni] = __builtin_bit_cast(f16x8, *(const short8*)(Bs + (wn * 64 + ni * 16 + l15) * 32 + lg * 8));
#pragma unroll
    for (int mi = 0; mi < 4; ++mi)
#pragma unroll
      for (int ni = 0; ni < 4; ++ni)
        acc[mi][ni] = __builtin_amdgcn_mfma_f32_16x16x32_f16(a[mi], bf[ni], acc[mi][ni], 0, 0, 0);
  }
  __syncthreads();
  unsigned short* T = lds;  // [128][136]
#pragma unroll
  for (int mi = 0; mi < 4; ++mi)
#pragma unroll
    for (int ni = 0; ni < 4; ++ni)
#pragma unroll
      for (int ii = 0; ii < 4; ++ii) {
        int sl = wm * 64 + mi * 16 + lg * 4 + ii;
        int nl = wn * 64 + ni * 16 + l15;
        T[nl * 136 + sl] = f2h(acc[mi][ni][ii]);
      }
  __syncthreads();
  int bidx = m0 >> 12;
  int s0 = m0 & (SLEN - 1);
  unsigned short* O = Vt + (size_t)bidx * DIM * SLEN;
  int nr = t >> 1, hf = t & 1;
#pragma unroll
  for (int j = 0; j < 8; ++j)
    *(short8*)(O + (size_t)(n0 + nr) * SLEN + s0 + hf * 64 + j * 8) =
        *(const short8*)(T + nr * 136 + hf * 64 + j * 8);
}

// ---------------- row softmax (in-place, causal mask, normalize) ----------------
__global__ __launch_bounds__(256) void softmax_kernel(
    unsigned short* __restrict__ S, size_t s_bstride) {
  __shared__ float redm[4], reds[4];
  const int r = blockIdx.x, b = blockIdx.y;
  unsigned short* Sb = S + (size_t)b * s_bstride;
  const int qt = r >> 7, rl = r & 127;
  const int ncols = (qt + 1) * 128;
  const size_t rowbase = (size_t)(qt * (qt + 1) / 2) * 16384 + (size_t)rl * 128;
  const int t = threadIdx.x, lane = t & 63, w = t >> 6;
  const int c0 = t * 16;
  const bool act = c0 < ncols;
  const float NEG = -3.0e38f;
  float sv[16];
  unsigned short* p = nullptr;
  if (act) {
    int ktile = c0 >> 7, cl = c0 & 127;
    p = Sb + rowbase + (size_t)ktile * 16384 + cl;
    V8 v0, v1; v0.v = *(const short8*)p; v1.v = *(const short8*)(p + 8);
#pragma unroll
    for (int j = 0; j < 8; ++j) {
      sv[j] = (c0 + j > r) ? NEG : h2f(v0.u[j]);
      sv[8 + j] = (c0 + 8 + j > r) ? NEG : h2f(v1.u[j]);
    }
  } else {
#pragma unroll
    for (int j = 0; j < 16; ++j) sv[j] = NEG;
  }
  float mx = NEG;
#pragma unroll
  for (int j = 0; j < 16; ++j) mx = fmaxf(mx, sv[j]);
#pragma unroll
  for (int d = 1; d < 64; d <<= 1) mx = fmaxf(mx, __shfl_xor(mx, d));
  if (lane == 0) redm[w] = mx;
  __syncthreads();
  mx = fmaxf(fmaxf(redm[0], redm[1]), fmaxf(redm[2], redm[3]));
  const float scl = 1.4426950408889634f / 27.712812921102035f;  // log2(e)/sqrt(768)
  float e[16], sm = 0.f;
#pragma unroll
  for (int j = 0; j < 16; ++j) { e[j] = exp2f((sv[j] - mx) * scl); sm += e[j]; }
#pragma unroll
  for (int d = 1; d < 64; d <<= 1) sm += __shfl_xor(sm, d);
  if (lane == 0) reds[w] = sm;
  __syncthreads();
  float inv = 1.0f / (reds[0] + reds[1] + reds[2] + reds[3]);
  if (act) {
    V8 o0, o1;
#pragma unroll
    for (int j = 0; j < 8; ++j) { o0.u[j] = f2h(e[j] * inv); o1.u[j] = f2h(e[8 + j] * inv); }
    *(short8*)p = o0.v;
    *(short8*)(p + 8) = o1.v;
  }
}

// ---------------- PV GEMM (packed P x Vt^T -> out fp32) ----------------
__global__ __launch_bounds__(256) void gemm_pv_kernel(
    const unsigned short* __restrict__ S, const unsigned short* __restrict__ Vt,
    float* __restrict__ Out, size_t s_bstride, int nb) {
  __shared__ __align__(16) unsigned short As[4096], Bs[4096];
  const int idx = blockIdx.x;
  const int qtr = idx / (6 * nb);
  const int rem = idx - qtr * 6 * nb;
  const int b = rem / 6, nt = rem % 6;
  const int qt = 31 - qtr;  // big tiles first
  const unsigned short* Sb = S + (size_t)b * s_bstride + (size_t)(qt * (qt + 1) / 2) * 16384;
  const unsigned short* Vb = Vt + (size_t)b * DIM * SLEN + (size_t)(nt * 128) * SLEN;
  float* Ob = Out + (size_t)b * SLEN * DIM + (size_t)(qt * 128) * DIM + nt * 128;
  const int t = threadIdx.x, lane = t & 63, w = t >> 6;
  const int l15 = lane & 15, lg = lane >> 4;
  const int wm = w >> 1, wn = w & 1;
  f32x4 acc[4][4];
#pragma unroll
  for (int a = 0; a < 4; ++a)
#pragma unroll
    for (int b2 = 0; b2 < 4; ++b2) acc[a][b2] = f32x4{0.f, 0.f, 0.f, 0.f};
  const int c0 = t, c1 = t + 256;
  const int r0 = c0 >> 2, k80 = (c0 & 3) * 8;
  const int r1 = c1 >> 2, k81 = (c1 & 3) * 8;
  const int ksteps = (qt + 1) * 4;
  for (int ks = 0; ks < ksteps; ++ks) {
    const int kb = ks * 32;
    const size_t atile = (size_t)(kb >> 7) * 16384 + (size_t)(kb & 127);
    __syncthreads();
    gl_lds16(Sb + atile + (size_t)r0 * 128 + k80, As + (size_t)c0 * 8);
    gl_lds16(Sb + atile + (size_t)r1 * 128 + k81, As + (size_t)c1 * 8);
    gl_lds16(Vb + (size_t)r0 * SLEN + kb + k80, Bs + (size_t)c0 * 8);
    gl_lds16(Vb + (size_t)r1 * SLEN + kb + k81, Bs + (size_t)c1 * 8);
    __syncthreads();
    f16x8 a[4], bf[4];
#pragma unroll
    for (int mi = 0; mi < 4; ++mi)
      a[mi] = __builtin_bit_cast(f16x8, *(const short8*)(As + (wm * 64 + mi * 16 + l15) * 32 + lg * 8));
#pragma unroll
    for (int ni = 0; ni < 4; ++ni)
      bf[ni] = __builtin_bit_cast(f16x8, *(const short8*)(Bs + (wn * 64 + ni * 16 + l15) * 32 + lg * 8));
#pragma unroll
    for (int mi = 0; mi < 4; ++mi)
#pragma unroll
      for (int ni = 0; ni < 4; ++ni)
        acc[mi][ni] = __builtin_amdgcn_mfma_f32_16x16x32_f16(a[mi], bf[ni], acc[mi][ni], 0, 0, 0);
  }
#pragma unroll
  for (int mi = 0; mi < 4; ++mi)
#pragma unroll
    for (int ni = 0; ni < 4; ++ni)
#pragma unroll
      for (int ii = 0; ii < 4; ++ii) {
        int rl = wm * 64 + mi * 16 + lg * 4 + ii;
        int cl = wn * 64 + ni * 16 + l15;
        Ob[(size_t)rl * DIM + cl] = acc[mi][ni][ii];
      }
}

// ---------------- host launcher ----------------
extern "C" void kernel_launch(void* const* d_in, const int* in_sizes, int n_in,
                              void* d_out, int out_size, void* d_ws, size_t ws_size,
                              hipStream_t stream) {
  const float* x  = (const float*)d_in[0];
  const float* Wq = (const float*)d_in[1];
  const float* Wk = (const float*)d_in[2];
  const float* Wv = (const float*)d_in[3];
  float* out = (float*)d_out;

  const size_t n_x = (size_t)BATCH * SLEN * DIM;  // 12,582,912
  const size_t S_PB = (size_t)NTILES * 16384;     // 8,650,752 elems/batch
  unsigned short* Q  = (unsigned short*)d_ws;
  unsigned short* K  = Q + n_x;
  unsigned short* Vt = K + n_x;
  unsigned short* xb = Vt + n_x;
  unsigned short* wt = xb + n_x;
  const size_t base_elems = 4 * n_x + (size_t)3 * DIM * DIM;  // 52,101,120
  const bool full = ws_size >= (base_elems + 4 * S_PB) * 2;   // 173,408,256 B

  convert_x_kernel<<<dim3((unsigned)(n_x / 8 / 256)), 256, 0, stream>>>(x, xb);
  transpose_w_kernel<<<dim3(DIM / 32, DIM / 32, 3), 256, 0, stream>>>(Wq, Wk, Wv, wt);

  if (full) {
    unsigned short* S = (unsigned short*)d_ws + base_elems;
    unsigned short* Vn = S;  // V (untransposed) overlays S start; dead before qk
    gemm8_kernel<0><<<dim3(64, 3, 3), 512, 0, stream>>>(xb, wt, Q, K, Vn, 0, 0);
    transpose_v_kernel<<<dim3(SLEN / 64, DIM / 64, BATCH), 256, 0, stream>>>(Vn, Vt);
    gemm8_kernel<1><<<dim3(NT256, BATCH), 512, 0, stream>>>(
        Q, K, S, nullptr, nullptr, (size_t)SLEN * DIM, S_PB);
    softmax_kernel<<<dim3(SLEN, BATCH), 256, 0, stream>>>(S, S_PB);
    gemm_pv_kernel<<<dim3(32 * 6 * BATCH), 256, 0, stream>>>(S, Vt, out, S_PB, BATCH);
  } else {
    gemm8_kernel<0><<<dim3(64, 3, 2), 512, 0, stream>>>(xb, wt, Q, K, nullptr, 0, 0);
    gemm_v128_kernel<<<dim3((BATCH * SLEN) / 128, DIM / 128), 256, 0, stream>>>(xb, wt, Vt);
    unsigned short* S = xb;  // overlay dead xb region (25.2 MB >= 17.3 MB)
    for (int b = 0; b < BATCH; ++b) {
      const size_t qo = (size_t)b * SLEN * DIM;
      gemm8_kernel<1><<<dim3(NT256, 1), 512, 0, stream>>>(
          Q + qo, K + qo, S, nullptr, nullptr, 0, 0);
      softmax_kernel<<<dim3(SLEN, 1), 256, 0, stream>>>(S, 0);
      gemm_pv_kernel<<<dim3(32 * 6), 256, 0, stream>>>(
          S, Vt + (size_t)b * DIM * SLEN, out + qo, 0, 1);
    }
  }
}

// Round 5
// 298.765 us; speedup vs baseline: 1.1421x; 1.1421x over previous
//
#include <hip/hip_runtime.h>
#include <hip/hip_bf16.h>
#include <hip/hip_fp16.h>

#define DIM 768
#define SLEN 4096
#define BATCH 4
#define NTILES 528   // 128-granular causal tiles per batch (S layout)
#define NT256 136    // 256-granular causal tiles per batch (qk grid)
#define SPB ((size_t)NTILES * 16384)

typedef __attribute__((ext_vector_type(8))) short short8;
typedef __attribute__((ext_vector_type(4))) short short4v;
typedef __attribute__((ext_vector_type(4))) float f32x4;
typedef __attribute__((ext_vector_type(8))) _Float16 f16x8;

typedef __attribute__((address_space(1))) void gvoid;
typedef __attribute__((address_space(3))) void lvoid;

__device__ __forceinline__ void gl_lds16(const void* g, void* l) {
  __builtin_amdgcn_global_load_lds((gvoid*)g, (lvoid*)l, 16, 0, 0);
}

__device__ __forceinline__ unsigned short f2h(float x) {
  union { _Float16 h; unsigned short u; } c; c.h = (_Float16)x; return c.u;
}
__device__ __forceinline__ float h2f(unsigned short u) {
  union { _Float16 h; unsigned short u; } c; c.u = u; return (float)c.h;
}

union V8 { short8 v; unsigned short u[8]; };

// ---------------- kernel 1: x fp32 -> fp16 ----------------
__global__ __launch_bounds__(256) void convert_x_kernel(
    const float* __restrict__ x, unsigned short* __restrict__ xb) {
  size_t i = ((size_t)blockIdx.x * 256 + threadIdx.x) * 8;
  f32x4 a = *(const f32x4*)(x + i);
  f32x4 b = *(const f32x4*)(x + i + 4);
  V8 o;
#pragma unroll
  for (int j = 0; j < 4; ++j) { o.u[j] = f2h(a[j]); o.u[4 + j] = f2h(b[j]); }
  *(short8*)(xb + i) = o.v;
}

// ---------------- kernel 2: W [k][n] fp32 -> Wt [n][k] fp16 ----------------
__global__ __launch_bounds__(256) void transpose_w_kernel(
    const float* __restrict__ Wq, const float* __restrict__ Wk,
    const float* __restrict__ Wv, unsigned short* __restrict__ Wt) {
  __shared__ float Tl[32][33];
  const float* Wi = blockIdx.z == 0 ? Wq : (blockIdx.z == 1 ? Wk : Wv);
  unsigned short* Wo = Wt + (size_t)blockIdx.z * DIM * DIM;
  int k0 = blockIdx.x * 32, n0 = blockIdx.y * 32;
  int t = threadIdx.x;
  int r = t >> 3, c4 = (t & 7) * 4;
  f32x4 v = *(const f32x4*)(Wi + (size_t)(k0 + r) * DIM + n0 + c4);
#pragma unroll
  for (int j = 0; j < 4; ++j) Tl[r][c4 + j] = v[j];
  __syncthreads();
  short4v ov;
#pragma unroll
  for (int j = 0; j < 4; ++j) ov[j] = (short)f2h(Tl[c4 + j][r]);
  *(short4v*)(Wo + (size_t)(n0 + r) * DIM + k0 + c4) = ov;
}

// ============ 256x256 8-phase GEMM core (T2 swizzle + T3/T4 counted vmcnt + T5) ====
// SYNC RULE (round-3 post-mortem): vmcnt(N) only covers the waiting wave's own
// loads; an s_barrier must sit between the wait and any wave's ds_read of the
// staged tile. Waits at end of P0 and end of P3; prologue vmcnt(4)+barrier.

#define STAGE(src, row0, kb, ldsoff)                                              \
  {                                                                               \
    gl_lds16((src) + (size_t)((row0) + rA) * DIM + (kb) + cA,                     \
             ldsb + (ldsoff) + t * 16);                                           \
    gl_lds16((src) + (size_t)((row0) + 64 + rA) * DIM + (kb) + cA,                \
             ldsb + (ldsoff) + 8192 + t * 16);                                    \
  }

// generic half-tile stage: 128 rows x 64 f16 from (srcp + r*stride)
#define STAGEP(srcp, stride, ldsoff)                                              \
  {                                                                               \
    gl_lds16((srcp) + (size_t)rA * (stride) + cA, ldsb + (ldsoff) + t * 16);      \
    gl_lds16((srcp) + (size_t)(64 + rA) * (stride) + cA,                          \
             ldsb + (ldsoff) + 8192 + t * 16);                                    \
  }

#define QPHASE(MH, CHB, STG, VMW)                                                 \
  {                                                                               \
    f16x8 afr[4];                                                                 \
    _Pragma("unroll") for (int j = 0; j < 4; ++j)                                 \
        afr[j] = __builtin_bit_cast(f16x8, *(const short8*)(ldsb + aB +           \
                 (MH) * 16384 + (j * 32 + arow) * 128 + (CHB)));                  \
    if ((MH) == 0) {                                                              \
      _Pragma("unroll") for (int n = 0; n < 4; ++n)                               \
          bfr[n] = __builtin_bit_cast(f16x8, *(const short8*)(ldsb + bB +         \
                   bh * 16384 + (brow + n * 16) * 128 + (CHB)));                  \
    }                                                                             \
    STG;                                                                          \
    VMW;                                                                          \
    asm volatile("s_barrier" ::: "memory");                                       \
    asm volatile("s_waitcnt lgkmcnt(0)" ::: "memory");                            \
    __builtin_amdgcn_sched_barrier(0);                                            \
    __builtin_amdgcn_s_setprio(1);                                                \
    _Pragma("unroll") for (int j = 0; j < 4; ++j)                                 \
      _Pragma("unroll") for (int n = 0; n < 4; ++n)                               \
        acc[(MH) * 4 + j][n] = __builtin_amdgcn_mfma_f32_16x16x32_f16(            \
            afr[j], bfr[n], acc[(MH) * 4 + j][n], 0, 0, 0);                       \
    __builtin_amdgcn_s_setprio(0);                                                \
    __builtin_amdgcn_sched_barrier(0);                                            \
    asm volatile("s_barrier" ::: "memory");                                       \
  }

// MODE 0: C = A(xb) x B(wt_z)^T -> Q or K (z=blockIdx.z in {0,1}).
// MODE 1: causal qk 256-tiles -> packed-128 S scatter.
// MODE 2: Vt[e][s] = A(wt_v) x B(xb)^T  (swapped roles; out ld = SLEN).
template <int MODE>
__global__ __launch_bounds__(512, 2) void gemm8_kernel(
    const unsigned short* __restrict__ Ag, const unsigned short* __restrict__ Bg,
    unsigned short* __restrict__ o0, unsigned short* __restrict__ o1,
    size_t stAB, size_t stS) {
  __shared__ __align__(16) unsigned short lds[65536];  // 128 KiB
  char* ldsb = (char*)lds;
  const int t = threadIdx.x;
  const int lane = t & 63, w = t >> 6;
  const int l15 = lane & 15, lg = lane >> 4;
  const int wr = w >> 2, wc = w & 3;

  int m0, n0, qt = 0, kt = 0;
  const unsigned short *A, *B;
  unsigned short* Co = nullptr;
  unsigned short* Sb = nullptr;
  if (MODE == 0) {
    m0 = blockIdx.x * 256; n0 = blockIdx.y * 256;
    A = Ag; B = Bg + (size_t)blockIdx.z * DIM * DIM;
    Co = blockIdx.z == 0 ? o0 : o1;
  } else if (MODE == 2) {
    m0 = blockIdx.y * 256; n0 = blockIdx.x * 256;
    A = Ag; B = Bg;
    Co = o0;
  } else {
    const int i = blockIdx.x, b = blockIdx.y;
    qt = (int)((sqrtf(8.f * i + 1.f) - 1.f) * 0.5f);
    while ((qt + 1) * (qt + 2) / 2 <= i) ++qt;
    while (qt * (qt + 1) / 2 > i) --qt;
    kt = i - qt * (qt + 1) / 2;
    m0 = qt * 256; n0 = kt * 256;
    A = Ag + (size_t)b * stAB; B = Bg + (size_t)b * stAB;
    Sb = o0 + (size_t)b * stS;
  }

  const int rA = t >> 3;
  const int cA = (((t & 7) ^ ((t >> 3) & 7)) << 3);  // inverse-swizzled src chunk
  const int ch0 = ((lg ^ (l15 & 7)) << 4);           // swizzled ds_read chunk byte
  const int arow = wr * 16 + l15;
  const int bh = wc >> 1;
  const int brow = (wc & 1) * 64 + l15;

  f32x4 acc[8][4];
#pragma unroll
  for (int f = 0; f < 8; ++f)
#pragma unroll
    for (int n = 0; n < 4; ++n) acc[f][n] = f32x4{0.f, 0.f, 0.f, 0.f};

  // prologue: A0(0), B0(0), B1(0), A1(0), A0(1)
  STAGE(A, m0, 0, 0);
  STAGE(B, n0, 0, 65536);
  STAGE(B, n0 + 128, 0, 65536 + 16384);
  STAGE(A, m0 + 128, 0, 16384);
  STAGE(A, m0, 64, 32768);
  asm volatile("s_waitcnt vmcnt(4)" ::: "memory");
  asm volatile("s_barrier" ::: "memory");

  for (int tt = 0; tt < 12; ++tt) {
    const int bt = tt & 1;
    const int aB = bt * 32768;
    const int bB = 65536 + bt * 32768;
    const int aN = (1 - bt) * 32768;
    const int bN = 65536 + (1 - bt) * 32768;
    const int kb1 = (tt + 1 < 12 ? tt + 1 : 11) * 64;
    const int kb2 = (tt + 2 < 12 ? tt + 2 : 11) * 64;
    f16x8 bfr[4];
    QPHASE(0, ch0, STAGE(B, n0, kb1, bN),
           asm volatile("s_waitcnt vmcnt(4)" ::: "memory"));
    QPHASE(1, ch0, STAGE(B, n0 + 128, kb1, bN + 16384), (void)0);
    QPHASE(0, ch0 ^ 64, STAGE(A, m0 + 128, kb1, aN + 16384), (void)0);
    QPHASE(1, ch0 ^ 64, STAGE(A, m0, kb2, aB),
           asm volatile("s_waitcnt vmcnt(4)" ::: "memory"));
  }
  asm volatile("s_waitcnt vmcnt(0)" ::: "memory");

  if (MODE == 0) {
#pragma unroll
    for (int f = 0; f < 8; ++f) {
      const int row = m0 + f * 32 + wr * 16 + lg * 4;
#pragma unroll
      for (int n = 0; n < 4; ++n) {
        const int col = n0 + wc * 64 + n * 16 + l15;
#pragma unroll
        for (int ii = 0; ii < 4; ++ii)
          Co[(size_t)(row + ii) * DIM + col] = f2h(acc[f][n][ii]);
      }
    }
  } else if (MODE == 2) {
    const int bb = n0 >> 12;
    unsigned short* O = Co + (size_t)bb * DIM * SLEN;
#pragma unroll
    for (int f = 0; f < 8; ++f) {
      const int row = m0 + f * 32 + wr * 16 + lg * 4;  // e
#pragma unroll
      for (int n = 0; n < 4; ++n) {
        const int sl = (n0 + wc * 64 + n * 16 + l15) & (SLEN - 1);
#pragma unroll
        for (int ii = 0; ii < 4; ++ii)
          O[(size_t)(row + ii) * SLEN + sl] = f2h(acc[f][n][ii]);
      }
    }
  } else {
#pragma unroll
    for (int f = 0; f < 8; ++f) {
      const int rl = (f * 32 + wr * 16 + lg * 4) & 127;
      const int Q128 = qt * 2 + (f >= 4 ? 1 : 0);
      const int K128 = kt * 2 + (wc >> 1);
      if (K128 > Q128) continue;
      const size_t tb = (size_t)(Q128 * (Q128 + 1) / 2 + K128) * 16384;
#pragma unroll
      for (int n = 0; n < 4; ++n) {
        const int cl = ((wc & 1) * 64 + n * 16 + l15);
#pragma unroll
        for (int ii = 0; ii < 4; ++ii)
          Sb[tb + (size_t)(rl + ii) * 128 + cl] = f2h(acc[f][n][ii]);
      }
    }
  }
}

// ---------------- row softmax (in-place, causal mask, normalize) ----------------
__global__ __launch_bounds__(256) void softmax_kernel(
    unsigned short* __restrict__ S, size_t s_bstride) {
  __shared__ float redm[4], reds[4];
  const int r = blockIdx.x, b = blockIdx.y;
  unsigned short* Sb = S + (size_t)b * s_bstride;
  const int qt = r >> 7, rl = r & 127;
  const int ncols = (qt + 1) * 128;
  const size_t rowbase = (size_t)(qt * (qt + 1) / 2) * 16384 + (size_t)rl * 128;
  const int t = threadIdx.x, lane = t & 63, w = t >> 6;
  const int c0 = t * 16;
  const bool act = c0 < ncols;
  const float NEG = -3.0e38f;
  float sv[16];
  unsigned short* p = nullptr;
  if (act) {
    int ktile = c0 >> 7, cl = c0 & 127;
    p = Sb + rowbase + (size_t)ktile * 16384 + cl;
    V8 v0, v1; v0.v = *(const short8*)p; v1.v = *(const short8*)(p + 8);
#pragma unroll
    for (int j = 0; j < 8; ++j) {
      sv[j] = (c0 + j > r) ? NEG : h2f(v0.u[j]);
      sv[8 + j] = (c0 + 8 + j > r) ? NEG : h2f(v1.u[j]);
    }
  } else {
#pragma unroll
    for (int j = 0; j < 16; ++j) sv[j] = NEG;
  }
  float mx = NEG;
#pragma unroll
  for (int j = 0; j < 16; ++j) mx = fmaxf(mx, sv[j]);
#pragma unroll
  for (int d = 1; d < 64; d <<= 1) mx = fmaxf(mx, __shfl_xor(mx, d));
  if (lane == 0) redm[w] = mx;
  __syncthreads();
  mx = fmaxf(fmaxf(redm[0], redm[1]), fmaxf(redm[2], redm[3]));
  const float scl = 1.4426950408889634f / 27.712812921102035f;  // log2(e)/sqrt(768)
  float e[16], sm = 0.f;
#pragma unroll
  for (int j = 0; j < 16; ++j) { e[j] = exp2f((sv[j] - mx) * scl); sm += e[j]; }
#pragma unroll
  for (int d = 1; d < 64; d <<= 1) sm += __shfl_xor(sm, d);
  if (lane == 0) reds[w] = sm;
  __syncthreads();
  float inv = 1.0f / (reds[0] + reds[1] + reds[2] + reds[3]);
  if (act) {
    V8 o0, o1;
#pragma unroll
    for (int j = 0; j < 8; ++j) { o0.u[j] = f2h(e[j] * inv); o1.u[j] = f2h(e[8 + j] * inv); }
    *(short8*)p = o0.v;
    *(short8*)(p + 8) = o1.v;
  }
}

// ---------------- zero the 128x128 f16 scratch tile ----------------
__global__ __launch_bounds__(256) void zero_tile_kernel(unsigned short* __restrict__ z) {
  ((short8*)z)[blockIdx.x * 256 + threadIdx.x] = short8{0, 0, 0, 0, 0, 0, 0, 0};
}

// ---------------- PV: 256x256 8-phase, balanced split-K ----------------
// Block rank table (desc by k-length). mt 0..7: single primary seg.
// mt 8..15: seg0 (primary, writes out) + seg1 (writes fp32 partial).
__device__ const int pv_mt[24]  = {15,15,7,14,14,13,13,6,12,12,11,11,5,10,10,9,9,4,8,8,3,2,1,0};
__device__ const int pv_ks0[24] = {0,32,0,0,30,0,28,0,0,26,0,24,0,0,22,0,20,0,0,18,0,0,0,0};
__device__ const int pv_kl[24]  = {32,32,32,30,30,28,28,28,26,26,24,24,24,22,22,20,20,20,18,18,16,12,8,4};
__device__ const int pv_sec[24] = {0,1,0,0,1,0,1,0,0,1,0,1,0,0,1,0,1,0,0,1,0,0,0,0};

__global__ __launch_bounds__(512, 2) void pv256_kernel(
    const unsigned short* __restrict__ S, const unsigned short* __restrict__ Vt,
    const unsigned short* __restrict__ Zt, float* __restrict__ Out,
    float* __restrict__ Part) {
  __shared__ __align__(16) unsigned short lds[65536];
  char* ldsb = (char*)lds;
  const int t = threadIdx.x, lane = t & 63, w = t >> 6;
  const int l15 = lane & 15, lg = lane >> 4;
  const int wr = w >> 2, wc = w & 3;
  const int rank = blockIdx.x / 12, sub = blockIdx.x % 12;
  const int b = sub / 3, nt = sub % 3;
  const int mt = pv_mt[rank], ks0 = pv_ks0[rank], kl = pv_kl[rank];
  const int sec = pv_sec[rank];
  const int q0 = 2 * mt, q1 = 2 * mt + 1;
  const int kend = ks0 + kl;
  const unsigned short* Sbb = S + (size_t)b * SPB;
  const unsigned short* Vb = Vt + (size_t)b * DIM * SLEN + (size_t)(nt * 256) * SLEN;

  // A source for k-step ks, row-half with Q128=qh; zero tile above diagonal.
  auto asrc = [&](int ks, int qh) -> const unsigned short* {
    const int K128 = ks >> 1;
    const unsigned short* base =
        (K128 <= qh) ? Sbb + (size_t)(qh * (qh + 1) / 2 + K128) * 16384 : Zt;
    return base + (ks & 1) * 64;
  };

  const int rA = t >> 3;
  const int cA = (((t & 7) ^ ((t >> 3) & 7)) << 3);
  const int ch0 = ((lg ^ (l15 & 7)) << 4);
  const int arow = wr * 16 + l15;
  const int bh = wc >> 1;
  const int brow = (wc & 1) * 64 + l15;

  f32x4 acc[8][4];
#pragma unroll
  for (int f = 0; f < 8; ++f)
#pragma unroll
    for (int n = 0; n < 4; ++n) acc[f][n] = f32x4{0.f, 0.f, 0.f, 0.f};

  // prologue: A0(s0), B0(s0), B1(s0), A1(s0), A0(s0+1)
  const int ksp = (ks0 + 1 < kend) ? ks0 + 1 : kend - 1;
  STAGEP(asrc(ks0, q0), 128, 0);
  STAGEP(Vb + (size_t)ks0 * 64, SLEN, 65536);
  STAGEP(Vb + (size_t)128 * SLEN + (size_t)ks0 * 64, SLEN, 65536 + 16384);
  STAGEP(asrc(ks0, q1), 128, 16384);
  STAGEP(asrc(ksp, q0), 128, 32768);
  asm volatile("s_waitcnt vmcnt(4)" ::: "memory");
  asm volatile("s_barrier" ::: "memory");

  for (int it = 0; it < kl; ++it) {
    const int ts = ks0 + it;
    const int bt = it & 1;
    const int aB = bt * 32768;
    const int bB = 65536 + bt * 32768;
    const int aN = (1 - bt) * 32768;
    const int bN = 65536 + (1 - bt) * 32768;
    const int t1 = (ts + 1 < kend) ? ts + 1 : kend - 1;
    const int t2 = (ts + 2 < kend) ? ts + 2 : kend - 1;
    f16x8 bfr[4];
    QPHASE(0, ch0, STAGEP(Vb + (size_t)t1 * 64, SLEN, bN),
           asm volatile("s_waitcnt vmcnt(4)" ::: "memory"));
    QPHASE(1, ch0, STAGEP(Vb + (size_t)128 * SLEN + (size_t)t1 * 64, SLEN, bN + 16384),
           (void)0);
    QPHASE(0, ch0 ^ 64, STAGEP(asrc(t1, q1), 128, aN + 16384), (void)0);
    QPHASE(1, ch0 ^ 64, STAGEP(asrc(t2, q0), 128, aB),
           asm volatile("s_waitcnt vmcnt(4)" ::: "memory"));
  }
  asm volatile("s_waitcnt vmcnt(0)" ::: "memory");

  if (!sec) {
    float* Ob = Out + (size_t)b * SLEN * DIM + (size_t)(mt * 256) * DIM + nt * 256;
#pragma unroll
    for (int f = 0; f < 8; ++f) {
      const int rl = f * 32 + wr * 16 + lg * 4;
#pragma unroll
      for (int n = 0; n < 4; ++n) {
        const int cl = wc * 64 + n * 16 + l15;
#pragma unroll
        for (int ii = 0; ii < 4; ++ii)
          Ob[(size_t)(rl + ii) * DIM + cl] = acc[f][n][ii];
      }
    }
  } else {
    float* Pb = Part + (size_t)((b * 3 + nt) * 8 + (mt - 8)) * 65536;
#pragma unroll
    for (int f = 0; f < 8; ++f) {
      const int rl = f * 32 + wr * 16 + lg * 4;
#pragma unroll
      for (int n = 0; n < 4; ++n) {
        const int cl = wc * 64 + n * 16 + l15;
#pragma unroll
        for (int ii = 0; ii < 4; ++ii)
          Pb[(size_t)(rl + ii) * 256 + cl] = acc[f][n][ii];
      }
    }
  }
}

// ---------------- add secondary-segment partials into out ----------------
__global__ __launch_bounds__(256) void pv_reduce_kernel(
    const float* __restrict__ Part, float* __restrict__ Out) {
  const int bx = blockIdx.x;            // 0..6143
  const int p = bx >> 6;                // partial slot 0..95
  const int within = ((bx & 63) * 256 + threadIdx.x) * 4;
  const int mt = 8 + (p & 7);
  const int bnt = p >> 3, b = bnt / 3, nt = bnt % 3;
  const int r = within >> 8, c = within & 255;
  float* o = Out + (size_t)b * SLEN * DIM + (size_t)(mt * 256 + r) * DIM + nt * 256 + c;
  const f32x4 pv = *(const f32x4*)(Part + (size_t)p * 65536 + within);
  const f32x4 ov = *(const f32x4*)o;
  *(f32x4*)o = ov + pv;
}

// ---------------- fallback PV GEMM (packed P x Vt^T -> out fp32) ----------------
__global__ __launch_bounds__(256) void gemm_pv_kernel(
    const unsigned short* __restrict__ S, const unsigned short* __restrict__ Vt,
    float* __restrict__ Out, size_t s_bstride, int nb) {
  __shared__ __align__(16) unsigned short As[4096], Bs[4096];
  const int idx = blockIdx.x;
  const int qtr = idx / (6 * nb);
  const int rem = idx - qtr * 6 * nb;
  const int b = rem / 6, nt = rem % 6;
  const int qt = 31 - qtr;
  const unsigned short* Sb = S + (size_t)b * s_bstride + (size_t)(qt * (qt + 1) / 2) * 16384;
  const unsigned short* Vb = Vt + (size_t)b * DIM * SLEN + (size_t)(nt * 128) * SLEN;
  float* Ob = Out + (size_t)b * SLEN * DIM + (size_t)(qt * 128) * DIM + nt * 128;
  const int t = threadIdx.x, lane = t & 63, w = t >> 6;
  const int l15 = lane & 15, lg = lane >> 4;
  const int wm = w >> 1, wn = w & 1;
  f32x4 acc[4][4];
#pragma unroll
  for (int a = 0; a < 4; ++a)
#pragma unroll
    for (int b2 = 0; b2 < 4; ++b2) acc[a][b2] = f32x4{0.f, 0.f, 0.f, 0.f};
  const int c0 = t, c1 = t + 256;
  const int r0 = c0 >> 2, k80 = (c0 & 3) * 8;
  const int r1 = c1 >> 2, k81 = (c1 & 3) * 8;
  const int ksteps = (qt + 1) * 4;
  for (int ks = 0; ks < ksteps; ++ks) {
    const int kb = ks * 32;
    const size_t atile = (size_t)(kb >> 7) * 16384 + (size_t)(kb & 127);
    __syncthreads();
    gl_lds16(Sb + atile + (size_t)r0 * 128 + k80, As + (size_t)c0 * 8);
    gl_lds16(Sb + atile + (size_t)r1 * 128 + k81, As + (size_t)c1 * 8);
    gl_lds16(Vb + (size_t)r0 * SLEN + kb + k80, Bs + (size_t)c0 * 8);
    gl_lds16(Vb + (size_t)r1 * SLEN + kb + k81, Bs + (size_t)c1 * 8);
    __syncthreads();
    f16x8 a[4], bf[4];
#pragma unroll
    for (int mi = 0; mi < 4; ++mi)
      a[mi] = __builtin_bit_cast(f16x8, *(const short8*)(As + (wm * 64 + mi * 16 + l15) * 32 + lg * 8));
#pragma unroll
    for (int ni = 0; ni < 4; ++ni)
      bf[ni] = __builtin_bit_cast(f16x8, *(const short8*)(Bs + (wn * 64 + ni * 16 + l15) * 32 + lg * 8));
#pragma unroll
    for (int mi = 0; mi < 4; ++mi)
#pragma unroll
      for (int ni = 0; ni < 4; ++ni)
        acc[mi][ni] = __builtin_amdgcn_mfma_f32_16x16x32_f16(a[mi], bf[ni], acc[mi][ni], 0, 0, 0);
  }
#pragma unroll
  for (int mi = 0; mi < 4; ++mi)
#pragma unroll
    for (int ni = 0; ni < 4; ++ni)
#pragma unroll
      for (int ii = 0; ii < 4; ++ii) {
        int rl = wm * 64 + mi * 16 + lg * 4 + ii;
        int cl = wn * 64 + ni * 16 + l15;
        Ob[(size_t)rl * DIM + cl] = acc[mi][ni][ii];
      }
}

// ---------------- host launcher ----------------
extern "C" void kernel_launch(void* const* d_in, const int* in_sizes, int n_in,
                              void* d_out, int out_size, void* d_ws, size_t ws_size,
                              hipStream_t stream) {
  const float* x  = (const float*)d_in[0];
  const float* Wq = (const float*)d_in[1];
  const float* Wk = (const float*)d_in[2];
  const float* Wv = (const float*)d_in[3];
  float* out = (float*)d_out;

  const size_t n_x = (size_t)BATCH * SLEN * DIM;  // 12,582,912
  unsigned short* Q  = (unsigned short*)d_ws;
  unsigned short* K  = Q + n_x;
  unsigned short* Vt = K + n_x;
  unsigned short* xb = Vt + n_x;
  unsigned short* wt = xb + n_x;
  const size_t base_elems = 4 * n_x + (size_t)3 * DIM * DIM;  // 52,101,120
  const bool full = ws_size >= (base_elems + 4 * SPB) * 2;    // 173,408,256 B

  convert_x_kernel<<<dim3((unsigned)(n_x / 8 / 256)), 256, 0, stream>>>(x, xb);
  transpose_w_kernel<<<dim3(DIM / 32, DIM / 32, 3), 256, 0, stream>>>(Wq, Wk, Wv, wt);

  // QKV projections: Q,K row-major; V written transposed via swapped-operand GEMM
  gemm8_kernel<0><<<dim3(64, 3, 2), 512, 0, stream>>>(xb, wt, Q, K, 0, 0);
  gemm8_kernel<2><<<dim3(64, 3), 512, 0, stream>>>(
      wt + (size_t)2 * DIM * DIM, xb, Vt, nullptr, 0, 0);

  if (full) {
    unsigned short* S = (unsigned short*)d_ws + base_elems;
    zero_tile_kernel<<<8, 256, 0, stream>>>(wt);  // wt dead; first 16384 -> zero tile
    gemm8_kernel<1><<<dim3(NT256, BATCH), 512, 0, stream>>>(
        Q, K, S, nullptr, (size_t)SLEN * DIM, SPB);
    softmax_kernel<<<dim3(SLEN, BATCH), 256, 0, stream>>>(S, SPB);
    pv256_kernel<<<dim3(288), 512, 0, stream>>>(S, Vt, wt, out, (float*)xb);
    pv_reduce_kernel<<<dim3(6144), 256, 0, stream>>>((const float*)xb, out);
  } else {
    unsigned short* S = xb;  // overlay dead xb region (25.2 MB >= 17.3 MB)
    for (int b = 0; b < BATCH; ++b) {
      const size_t qo = (size_t)b * SLEN * DIM;
      gemm8_kernel<1><<<dim3(NT256, 1), 512, 0, stream>>>(
          Q + qo, K + qo, S, nullptr, 0, 0);
      softmax_kernel<<<dim3(SLEN, 1), 256, 0, stream>>>(S, 0);
      gemm_pv_kernel<<<dim3(32 * 6), 256, 0, stream>>>(
          S, Vt + (size_t)b * DIM * SLEN, out + qo, 0, 1);
    }
  }
}

// Round 6
// 294.422 us; speedup vs baseline: 1.1589x; 1.0148x over previous
//
#include <hip/hip_runtime.h>
#include <hip/hip_bf16.h>
#include <hip/hip_fp16.h>

#define DIM 768
#define SLEN 4096
#define BATCH 4
#define NTILES 528   // 128-granular causal tiles per batch (S layout)
#define NT256 136    // 256-granular causal tiles per batch (qk grid)
#define SPB ((size_t)NTILES * 16384)

typedef __attribute__((ext_vector_type(8))) short short8;
typedef __attribute__((ext_vector_type(4))) short short4v;
typedef __attribute__((ext_vector_type(4))) float f32x4;
typedef __attribute__((ext_vector_type(8))) _Float16 f16x8;

typedef __attribute__((address_space(1))) void gvoid;
typedef __attribute__((address_space(3))) void lvoid;

__device__ __forceinline__ void gl_lds16(const void* g, void* l) {
  __builtin_amdgcn_global_load_lds((gvoid*)g, (lvoid*)l, 16, 0, 0);
}

__device__ __forceinline__ unsigned short f2h(float x) {
  union { _Float16 h; unsigned short u; } c; c.h = (_Float16)x; return c.u;
}
__device__ __forceinline__ float h2f(unsigned short u) {
  union { _Float16 h; unsigned short u; } c; c.u = u; return (float)c.h;
}

union V8 { short8 v; unsigned short u[8]; };

// ---------------- kernel 1: x fp32 -> fp16 ----------------
__global__ __launch_bounds__(256) void convert_x_kernel(
    const float* __restrict__ x, unsigned short* __restrict__ xb) {
  size_t i = ((size_t)blockIdx.x * 256 + threadIdx.x) * 8;
  f32x4 a = *(const f32x4*)(x + i);
  f32x4 b = *(const f32x4*)(x + i + 4);
  V8 o;
#pragma unroll
  for (int j = 0; j < 4; ++j) { o.u[j] = f2h(a[j]); o.u[4 + j] = f2h(b[j]); }
  *(short8*)(xb + i) = o.v;
}

// ---------------- kernel 2: W [k][n] fp32 -> Wt [n][k] fp16 ----------------
__global__ __launch_bounds__(256) void transpose_w_kernel(
    const float* __restrict__ Wq, const float* __restrict__ Wk,
    const float* __restrict__ Wv, unsigned short* __restrict__ Wt) {
  __shared__ float Tl[32][33];
  const float* Wi = blockIdx.z == 0 ? Wq : (blockIdx.z == 1 ? Wk : Wv);
  unsigned short* Wo = Wt + (size_t)blockIdx.z * DIM * DIM;
  int k0 = blockIdx.x * 32, n0 = blockIdx.y * 32;
  int t = threadIdx.x;
  int r = t >> 3, c4 = (t & 7) * 4;
  f32x4 v = *(const f32x4*)(Wi + (size_t)(k0 + r) * DIM + n0 + c4);
#pragma unroll
  for (int j = 0; j < 4; ++j) Tl[r][c4 + j] = v[j];
  __syncthreads();
  short4v ov;
#pragma unroll
  for (int j = 0; j < 4; ++j) ov[j] = (short)f2h(Tl[c4 + j][r]);
  *(short4v*)(Wo + (size_t)(n0 + r) * DIM + k0 + c4) = ov;
}

// ============ 256x256 8-phase GEMM core, deep-pipelined (r6 schedule) ============
// Regions: A buf p @ p*32768 (A0 +0, A1 +16384); B buf p @ 65536+p*32768.
// Per tile t (buffer parity bt=t&1): P0 issues B1(t+1)->bN.B1, A1(t+1)->aN.A1
// (regions last read P2/P3(t-1)); P3 issues B0(t+2)->bB.B0, A0(t+2)->aB.A0
// (regions last read P2(t)); ONE s_waitcnt vmcnt(4) at P3-end: outstanding=12,
// wait-to-4 completes exactly tile t+1's 4 half-tiles (issued 3-5 phases back),
// leaving P3's own 4 issues in flight. Barriers separate wait from cross-wave
// ds_reads (round-3 rule). Prologue: 6 half-tiles, vmcnt(4)+barrier.

#define STAGE(src, row0, kb, ldsoff)                                              \
  {                                                                               \
    gl_lds16((src) + (size_t)((row0) + rA) * DIM + (kb) + cA,                     \
             ldsb + (ldsoff) + t * 16);                                           \
    gl_lds16((src) + (size_t)((row0) + 64 + rA) * DIM + (kb) + cA,                \
             ldsb + (ldsoff) + 8192 + t * 16);                                    \
  }

#define STAGEP(srcp, stride, ldsoff)                                              \
  {                                                                               \
    gl_lds16((srcp) + (size_t)rA * (stride) + cA, ldsb + (ldsoff) + t * 16);      \
    gl_lds16((srcp) + (size_t)(64 + rA) * (stride) + cA,                          \
             ldsb + (ldsoff) + 8192 + t * 16);                                    \
  }

#define QPHASE(MH, CHB, STG, VMW)                                                 \
  {                                                                               \
    f16x8 afr[4];                                                                 \
    _Pragma("unroll") for (int j = 0; j < 4; ++j)                                 \
        afr[j] = __builtin_bit_cast(f16x8, *(const short8*)(ldsb + aB +           \
                 (MH) * 16384 + (j * 32 + arow) * 128 + (CHB)));                  \
    if ((MH) == 0) {                                                              \
      _Pragma("unroll") for (int n = 0; n < 4; ++n)                               \
          bfr[n] = __builtin_bit_cast(f16x8, *(const short8*)(ldsb + bB +         \
                   bh * 16384 + (brow + n * 16) * 128 + (CHB)));                  \
    }                                                                             \
    STG;                                                                          \
    VMW;                                                                          \
    asm volatile("s_barrier" ::: "memory");                                       \
    asm volatile("s_waitcnt lgkmcnt(0)" ::: "memory");                            \
    __builtin_amdgcn_sched_barrier(0);                                            \
    __builtin_amdgcn_s_setprio(1);                                                \
    _Pragma("unroll") for (int j = 0; j < 4; ++j)                                 \
      _Pragma("unroll") for (int n = 0; n < 4; ++n)                               \
        acc[(MH) * 4 + j][n] = __builtin_amdgcn_mfma_f32_16x16x32_f16(            \
            afr[j], bfr[n], acc[(MH) * 4 + j][n], 0, 0, 0);                       \
    __builtin_amdgcn_s_setprio(0);                                                \
    __builtin_amdgcn_sched_barrier(0);                                            \
    asm volatile("s_barrier" ::: "memory");                                       \
  }

// MODE 0: merged qkv. 1-D grid 576, XCD-swizzled. z<2: C=A(xb)xB(wt_z)^T -> Q/K.
//         z==2: Vt[e][s] = A(wt_v) x B(xb)^T (swapped roles, out ld=SLEN).
// MODE 1: causal qk 256-tiles (x XCD-swizzled per batch) -> packed-128 S scatter.
template <int MODE>
__global__ __launch_bounds__(512, 2) void gemm8_kernel(
    const unsigned short* __restrict__ Ag, const unsigned short* __restrict__ Bg,
    unsigned short* __restrict__ o0, unsigned short* __restrict__ o1,
    unsigned short* __restrict__ o2, size_t stAB, size_t stS) {
  __shared__ __align__(16) unsigned short lds[65536];  // 128 KiB
  char* ldsb = (char*)lds;
  const int t = threadIdx.x;
  const int lane = t & 63, w = t >> 6;
  const int l15 = lane & 15, lg = lane >> 4;
  const int wr = w >> 2, wc = w & 3;

  int m0, n0, qt = 0, kt = 0, z = 0;
  const unsigned short *A, *B;
  unsigned short* Co = nullptr;
  unsigned short* Sb = nullptr;
  if (MODE == 0) {
    const int o = blockIdx.x;
    const int oi = (o & 7) * 72 + (o >> 3);  // 576 = 8*72, bijective
    const int mt = oi / 9, sub = oi - mt * 9;
    const int ntile = sub / 3;
    z = sub - ntile * 3;
    if (z < 2) {
      m0 = mt * 256; n0 = ntile * 256;
      A = Ag; B = Bg + (size_t)z * DIM * DIM;
      Co = z == 0 ? o0 : o1;
    } else {
      m0 = ntile * 256; n0 = mt * 256;  // m: e-dim, n: s-dim
      A = Bg + (size_t)2 * DIM * DIM; B = Ag;
      Co = o2;
    }
  } else {
    const int i0 = blockIdx.x, b = blockIdx.y;
    const int i = (i0 & 7) * 17 + (i0 >> 3);  // 136 = 8*17, bijective
    qt = (int)((sqrtf(8.f * i + 1.f) - 1.f) * 0.5f);
    while ((qt + 1) * (qt + 2) / 2 <= i) ++qt;
    while (qt * (qt + 1) / 2 > i) --qt;
    kt = i - qt * (qt + 1) / 2;
    m0 = qt * 256; n0 = kt * 256;
    A = Ag + (size_t)b * stAB; B = Bg + (size_t)b * stAB;
    Sb = o0 + (size_t)b * stS;
  }

  const int rA = t >> 3;
  const int cA = (((t & 7) ^ ((t >> 3) & 7)) << 3);  // inverse-swizzled src chunk
  const int ch0 = ((lg ^ (l15 & 7)) << 4);           // swizzled ds_read chunk byte
  const int arow = wr * 16 + l15;
  const int bh = wc >> 1;
  const int brow = (wc & 1) * 64 + l15;

  f32x4 acc[8][4];
#pragma unroll
  for (int f = 0; f < 8; ++f)
#pragma unroll
    for (int n = 0; n < 4; ++n) acc[f][n] = f32x4{0.f, 0.f, 0.f, 0.f};

  // prologue (FIFO): A0(0),B0(0),B1(0),A1(0),B0(1),A0(1) -> vmcnt(4) -> barrier
  STAGE(A, m0, 0, 0);
  STAGE(B, n0, 0, 65536);
  STAGE(B, n0 + 128, 0, 65536 + 16384);
  STAGE(A, m0 + 128, 0, 16384);
  STAGE(B, n0, 64, 65536 + 32768);
  STAGE(A, m0, 64, 32768);
  asm volatile("s_waitcnt vmcnt(4)" ::: "memory");
  asm volatile("s_barrier" ::: "memory");

  for (int tt = 0; tt < 12; ++tt) {
    const int bt = tt & 1;
    const int aB = bt * 32768;
    const int bB = 65536 + bt * 32768;
    const int aN = (1 - bt) * 32768;
    const int bN = 65536 + (1 - bt) * 32768;
    const int kb1 = (tt + 1 < 12 ? tt + 1 : 11) * 64;
    const int kb2 = (tt + 2 < 12 ? tt + 2 : 11) * 64;
    f16x8 bfr[4];
    QPHASE(0, ch0,
           STAGE(B, n0 + 128, kb1, bN + 16384); STAGE(A, m0 + 128, kb1, aN + 16384),
           (void)0);
    QPHASE(1, ch0, (void)0, (void)0);
    QPHASE(0, ch0 ^ 64, (void)0, (void)0);
    QPHASE(1, ch0 ^ 64,
           STAGE(B, n0, kb2, bB); STAGE(A, m0, kb2, aB),
           asm volatile("s_waitcnt vmcnt(4)" ::: "memory"));
  }
  asm volatile("s_waitcnt vmcnt(0)" ::: "memory");

  if (MODE == 0) {
    if (z < 2) {
#pragma unroll
      for (int f = 0; f < 8; ++f) {
        const int row = m0 + f * 32 + wr * 16 + lg * 4;
#pragma unroll
        for (int n = 0; n < 4; ++n) {
          const int col = n0 + wc * 64 + n * 16 + l15;
#pragma unroll
          for (int ii = 0; ii < 4; ++ii)
            Co[(size_t)(row + ii) * DIM + col] = f2h(acc[f][n][ii]);
        }
      }
    } else {
      const int bb = n0 >> 12;
      unsigned short* O = Co + (size_t)bb * DIM * SLEN;
#pragma unroll
      for (int f = 0; f < 8; ++f) {
        const int row = m0 + f * 32 + wr * 16 + lg * 4;  // e
#pragma unroll
        for (int n = 0; n < 4; ++n) {
          const int sl = (n0 + wc * 64 + n * 16 + l15) & (SLEN - 1);
#pragma unroll
          for (int ii = 0; ii < 4; ++ii)
            O[(size_t)(row + ii) * SLEN + sl] = f2h(acc[f][n][ii]);
        }
      }
    }
  } else {
#pragma unroll
    for (int f = 0; f < 8; ++f) {
      const int rl = (f * 32 + wr * 16 + lg * 4) & 127;
      const int Q128 = qt * 2 + (f >= 4 ? 1 : 0);
      const int K128 = kt * 2 + (wc >> 1);
      if (K128 > Q128) continue;
      const size_t tb = (size_t)(Q128 * (Q128 + 1) / 2 + K128) * 16384;
#pragma unroll
      for (int n = 0; n < 4; ++n) {
        const int cl = ((wc & 1) * 64 + n * 16 + l15);
#pragma unroll
        for (int ii = 0; ii < 4; ++ii)
          Sb[tb + (size_t)(rl + ii) * 128 + cl] = f2h(acc[f][n][ii]);
      }
    }
  }
}

// ---------------- row softmax (in-place, causal mask, normalize) ----------------
__global__ __launch_bounds__(256) void softmax_kernel(
    unsigned short* __restrict__ S, size_t s_bstride) {
  __shared__ float redm[4], reds[4];
  const int r = blockIdx.x, b = blockIdx.y;
  unsigned short* Sb = S + (size_t)b * s_bstride;
  const int qt = r >> 7, rl = r & 127;
  const int ncols = (qt + 1) * 128;
  const size_t rowbase = (size_t)(qt * (qt + 1) / 2) * 16384 + (size_t)rl * 128;
  const int t = threadIdx.x, lane = t & 63, w = t >> 6;
  const int c0 = t * 16;
  const bool act = c0 < ncols;
  const float NEG = -3.0e38f;
  float sv[16];
  unsigned short* p = nullptr;
  if (act) {
    int ktile = c0 >> 7, cl = c0 & 127;
    p = Sb + rowbase + (size_t)ktile * 16384 + cl;
    V8 v0, v1; v0.v = *(const short8*)p; v1.v = *(const short8*)(p + 8);
#pragma unroll
    for (int j = 0; j < 8; ++j) {
      sv[j] = (c0 + j > r) ? NEG : h2f(v0.u[j]);
      sv[8 + j] = (c0 + 8 + j > r) ? NEG : h2f(v1.u[j]);
    }
  } else {
#pragma unroll
    for (int j = 0; j < 16; ++j) sv[j] = NEG;
  }
  float mx = NEG;
#pragma unroll
  for (int j = 0; j < 16; ++j) mx = fmaxf(mx, sv[j]);
#pragma unroll
  for (int d = 1; d < 64; d <<= 1) mx = fmaxf(mx, __shfl_xor(mx, d));
  if (lane == 0) redm[w] = mx;
  __syncthreads();
  mx = fmaxf(fmaxf(redm[0], redm[1]), fmaxf(redm[2], redm[3]));
  const float scl = 1.4426950408889634f / 27.712812921102035f;  // log2(e)/sqrt(768)
  float e[16], sm = 0.f;
#pragma unroll
  for (int j = 0; j < 16; ++j) { e[j] = exp2f((sv[j] - mx) * scl); sm += e[j]; }
#pragma unroll
  for (int d = 1; d < 64; d <<= 1) sm += __shfl_xor(sm, d);
  if (lane == 0) reds[w] = sm;
  __syncthreads();
  float inv = 1.0f / (reds[0] + reds[1] + reds[2] + reds[3]);
  if (act) {
    V8 o0, o1;
#pragma unroll
    for (int j = 0; j < 8; ++j) { o0.u[j] = f2h(e[j] * inv); o1.u[j] = f2h(e[8 + j] * inv); }
    *(short8*)p = o0.v;
    *(short8*)(p + 8) = o1.v;
  }
}

// ---------------- zero the 128x128 f16 scratch tile ----------------
__global__ __launch_bounds__(256) void zero_tile_kernel(unsigned short* __restrict__ z) {
  ((short8*)z)[blockIdx.x * 256 + threadIdx.x] = short8{0, 0, 0, 0, 0, 0, 0, 0};
}

// ---------------- PV: 256x256 8-phase, balanced split-K ----------------
__device__ const int pv_mt[24]  = {15,15,7,14,14,13,13,6,12,12,11,11,5,10,10,9,9,4,8,8,3,2,1,0};
__device__ const int pv_ks0[24] = {0,32,0,0,30,0,28,0,0,26,0,24,0,0,22,0,20,0,0,18,0,0,0,0};
__device__ const int pv_kl[24]  = {32,32,32,30,30,28,28,28,26,26,24,24,24,22,22,20,20,20,18,18,16,12,8,4};
__device__ const int pv_sec[24] = {0,1,0,0,1,0,1,0,0,1,0,1,0,0,1,0,1,0,0,1,0,0,0,0};

__global__ __launch_bounds__(512, 2) void pv256_kernel(
    const unsigned short* __restrict__ S, const unsigned short* __restrict__ Vt,
    const unsigned short* __restrict__ Zt, float* __restrict__ Out,
    float* __restrict__ Part) {
  __shared__ __align__(16) unsigned short lds[65536];
  char* ldsb = (char*)lds;
  const int t = threadIdx.x, lane = t & 63, w = t >> 6;
  const int l15 = lane & 15, lg = lane >> 4;
  const int wr = w >> 2, wc = w & 3;
  const int rank = blockIdx.x / 12, sub = blockIdx.x % 12;
  const int b = sub / 3, nt = sub % 3;
  const int mt = pv_mt[rank], ks0 = pv_ks0[rank], kl = pv_kl[rank];
  const int sec = pv_sec[rank];
  const int q0 = 2 * mt, q1 = 2 * mt + 1;
  const int kend = ks0 + kl;
  const unsigned short* Sbb = S + (size_t)b * SPB;
  const unsigned short* Vb = Vt + (size_t)b * DIM * SLEN + (size_t)(nt * 256) * SLEN;

  auto asrc = [&](int ks, int qh) -> const unsigned short* {
    const int K128 = ks >> 1;
    const unsigned short* base =
        (K128 <= qh) ? Sbb + (size_t)(qh * (qh + 1) / 2 + K128) * 16384 : Zt;
    return base + (ks & 1) * 64;
  };

  const int rA = t >> 3;
  const int cA = (((t & 7) ^ ((t >> 3) & 7)) << 3);
  const int ch0 = ((lg ^ (l15 & 7)) << 4);
  const int arow = wr * 16 + l15;
  const int bh = wc >> 1;
  const int brow = (wc & 1) * 64 + l15;

  f32x4 acc[8][4];
#pragma unroll
  for (int f = 0; f < 8; ++f)
#pragma unroll
    for (int n = 0; n < 4; ++n) acc[f][n] = f32x4{0.f, 0.f, 0.f, 0.f};

  // prologue: A0(0),B0(0),B1(0),A1(0),B0(1),A0(1) (tile indices rel. ks0)
  const int ksp = (ks0 + 1 < kend) ? ks0 + 1 : kend - 1;
  STAGEP(asrc(ks0, q0), 128, 0);
  STAGEP(Vb + (size_t)ks0 * 64, SLEN, 65536);
  STAGEP(Vb + (size_t)128 * SLEN + (size_t)ks0 * 64, SLEN, 65536 + 16384);
  STAGEP(asrc(ks0, q1), 128, 16384);
  STAGEP(Vb + (size_t)ksp * 64, SLEN, 65536 + 32768);
  STAGEP(asrc(ksp, q0), 128, 32768);
  asm volatile("s_waitcnt vmcnt(4)" ::: "memory");
  asm volatile("s_barrier" ::: "memory");

  for (int it = 0; it < kl; ++it) {
    const int ts = ks0 + it;
    const int bt = it & 1;
    const int aB = bt * 32768;
    const int bB = 65536 + bt * 32768;
    const int aN = (1 - bt) * 32768;
    const int bN = 65536 + (1 - bt) * 32768;
    const int t1 = (ts + 1 < kend) ? ts + 1 : kend - 1;
    const int t2 = (ts + 2 < kend) ? ts + 2 : kend - 1;
    f16x8 bfr[4];
    QPHASE(0, ch0,
           STAGEP(Vb + (size_t)128 * SLEN + (size_t)t1 * 64, SLEN, bN + 16384);
           STAGEP(asrc(t1, q1), 128, aN + 16384),
           (void)0);
    QPHASE(1, ch0, (void)0, (void)0);
    QPHASE(0, ch0 ^ 64, (void)0, (void)0);
    QPHASE(1, ch0 ^ 64,
           STAGEP(Vb + (size_t)t2 * 64, SLEN, bB);
           STAGEP(asrc(t2, q0), 128, aB),
           asm volatile("s_waitcnt vmcnt(4)" ::: "memory"));
  }
  asm volatile("s_waitcnt vmcnt(0)" ::: "memory");

  if (!sec) {
    float* Ob = Out + (size_t)b * SLEN * DIM + (size_t)(mt * 256) * DIM + nt * 256;
#pragma unroll
    for (int f = 0; f < 8; ++f) {
      const int rl = f * 32 + wr * 16 + lg * 4;
#pragma unroll
      for (int n = 0; n < 4; ++n) {
        const int cl = wc * 64 + n * 16 + l15;
#pragma unroll
        for (int ii = 0; ii < 4; ++ii)
          Ob[(size_t)(rl + ii) * DIM + cl] = acc[f][n][ii];
      }
    }
  } else {
    float* Pb = Part + (size_t)((b * 3 + nt) * 8 + (mt - 8)) * 65536;
#pragma unroll
    for (int f = 0; f < 8; ++f) {
      const int rl = f * 32 + wr * 16 + lg * 4;
#pragma unroll
      for (int n = 0; n < 4; ++n) {
        const int cl = wc * 64 + n * 16 + l15;
#pragma unroll
        for (int ii = 0; ii < 4; ++ii)
          Pb[(size_t)(rl + ii) * 256 + cl] = acc[f][n][ii];
      }
    }
  }
}

// ---------------- add secondary-segment partials into out ----------------
__global__ __launch_bounds__(256) void pv_reduce_kernel(
    const float* __restrict__ Part, float* __restrict__ Out) {
  const int bx = blockIdx.x;            // 0..6143
  const int p = bx >> 6;                // partial slot 0..95
  const int within = ((bx & 63) * 256 + threadIdx.x) * 4;
  const int mt = 8 + (p & 7);
  const int bnt = p >> 3, b = bnt / 3, nt = bnt % 3;
  const int r = within >> 8, c = within & 255;
  float* o = Out + (size_t)b * SLEN * DIM + (size_t)(mt * 256 + r) * DIM + nt * 256 + c;
  const f32x4 pv = *(const f32x4*)(Part + (size_t)p * 65536 + within);
  const f32x4 ov = *(const f32x4*)o;
  *(f32x4*)o = ov + pv;
}

// ---------------- fallback PV GEMM (packed P x Vt^T -> out fp32) ----------------
__global__ __launch_bounds__(256) void gemm_pv_kernel(
    const unsigned short* __restrict__ S, const unsigned short* __restrict__ Vt,
    float* __restrict__ Out, size_t s_bstride, int nb) {
  __shared__ __align__(16) unsigned short As[4096], Bs[4096];
  const int idx = blockIdx.x;
  const int qtr = idx / (6 * nb);
  const int rem = idx - qtr * 6 * nb;
  const int b = rem / 6, nt = rem % 6;
  const int qt = 31 - qtr;
  const unsigned short* Sb = S + (size_t)b * s_bstride + (size_t)(qt * (qt + 1) / 2) * 16384;
  const unsigned short* Vb = Vt + (size_t)b * DIM * SLEN + (size_t)(nt * 128) * SLEN;
  float* Ob = Out + (size_t)b * SLEN * DIM + (size_t)(qt * 128) * DIM + nt * 128;
  const int t = threadIdx.x, lane = t & 63, w = t >> 6;
  const int l15 = lane & 15, lg = lane >> 4;
  const int wm = w >> 1, wn = w & 1;
  f32x4 acc[4][4];
#pragma unroll
  for (int a = 0; a < 4; ++a)
#pragma unroll
    for (int b2 = 0; b2 < 4; ++b2) acc[a][b2] = f32x4{0.f, 0.f, 0.f, 0.f};
  const int c0 = t, c1 = t + 256;
  const int r0 = c0 >> 2, k80 = (c0 & 3) * 8;
  const int r1 = c1 >> 2, k81 = (c1 & 3) * 8;
  const int ksteps = (qt + 1) * 4;
  for (int ks = 0; ks < ksteps; ++ks) {
    const int kb = ks * 32;
    const size_t atile = (size_t)(kb >> 7) * 16384 + (size_t)(kb & 127);
    __syncthreads();
    gl_lds16(Sb + atile + (size_t)r0 * 128 + k80, As + (size_t)c0 * 8);
    gl_lds16(Sb + atile + (size_t)r1 * 128 + k81, As + (size_t)c1 * 8);
    gl_lds16(Vb + (size_t)r0 * SLEN + kb + k80, Bs + (size_t)c0 * 8);
    gl_lds16(Vb + (size_t)r1 * SLEN + kb + k81, Bs + (size_t)c1 * 8);
    __syncthreads();
    f16x8 a[4], bf[4];
#pragma unroll
    for (int mi = 0; mi < 4; ++mi)
      a[mi] = __builtin_bit_cast(f16x8, *(const short8*)(As + (wm * 64 + mi * 16 + l15) * 32 + lg * 8));
#pragma unroll
    for (int ni = 0; ni < 4; ++ni)
      bf[ni] = __builtin_bit_cast(f16x8, *(const short8*)(Bs + (wn * 64 + ni * 16 + l15) * 32 + lg * 8));
#pragma unroll
    for (int mi = 0; mi < 4; ++mi)
#pragma unroll
      for (int ni = 0; ni < 4; ++ni)
        acc[mi][ni] = __builtin_amdgcn_mfma_f32_16x16x32_f16(a[mi], bf[ni], acc[mi][ni], 0, 0, 0);
  }
#pragma unroll
  for (int mi = 0; mi < 4; ++mi)
#pragma unroll
    for (int ni = 0; ni < 4; ++ni)
#pragma unroll
      for (int ii = 0; ii < 4; ++ii) {
        int rl = wm * 64 + mi * 16 + lg * 4 + ii;
        int cl = wn * 64 + ni * 16 + l15;
        Ob[(size_t)rl * DIM + cl] = acc[mi][ni][ii];
      }
}

// ---------------- host launcher ----------------
extern "C" void kernel_launch(void* const* d_in, const int* in_sizes, int n_in,
                              void* d_out, int out_size, void* d_ws, size_t ws_size,
                              hipStream_t stream) {
  const float* x  = (const float*)d_in[0];
  const float* Wq = (const float*)d_in[1];
  const float* Wk = (const float*)d_in[2];
  const float* Wv = (const float*)d_in[3];
  float* out = (float*)d_out;

  const size_t n_x = (size_t)BATCH * SLEN * DIM;  // 12,582,912
  unsigned short* Q  = (unsigned short*)d_ws;
  unsigned short* K  = Q + n_x;
  unsigned short* Vt = K + n_x;
  unsigned short* xb = Vt + n_x;
  unsigned short* wt = xb + n_x;
  const size_t base_elems = 4 * n_x + (size_t)3 * DIM * DIM;  // 52,101,120
  const bool full = ws_size >= (base_elems + 4 * SPB) * 2;    // 173,408,256 B

  convert_x_kernel<<<dim3((unsigned)(n_x / 8 / 256)), 256, 0, stream>>>(x, xb);
  transpose_w_kernel<<<dim3(DIM / 32, DIM / 32, 3), 256, 0, stream>>>(Wq, Wk, Wv, wt);

  // merged QKV: Q,K row-major + V transposed, one 576-block dispatch
  gemm8_kernel<0><<<dim3(576), 512, 0, stream>>>(xb, wt, Q, K, Vt, 0, 0);

  if (full) {
    unsigned short* S = (unsigned short*)d_ws + base_elems;
    zero_tile_kernel<<<8, 256, 0, stream>>>(wt);  // wt dead; first 16384 -> zero tile
    gemm8_kernel<1><<<dim3(NT256, BATCH), 512, 0, stream>>>(
        Q, K, S, nullptr, nullptr, (size_t)SLEN * DIM, SPB);
    softmax_kernel<<<dim3(SLEN, BATCH), 256, 0, stream>>>(S, SPB);
    pv256_kernel<<<dim3(288), 512, 0, stream>>>(S, Vt, wt, out, (float*)xb);
    pv_reduce_kernel<<<dim3(6144), 256, 0, stream>>>((const float*)xb, out);
  } else {
    unsigned short* S = xb;  // overlay dead xb region (25.2 MB >= 17.3 MB)
    for (int b = 0; b < BATCH; ++b) {
      const size_t qo = (size_t)b * SLEN * DIM;
      gemm8_kernel<1><<<dim3(NT256, 1), 512, 0, stream>>>(
          Q + qo, K + qo, S, nullptr, nullptr, 0, 0);
      softmax_kernel<<<dim3(SLEN, 1), 256, 0, stream>>>(S, 0);
      gemm_pv_kernel<<<dim3(32 * 6), 256, 0, stream>>>(
          S, Vt + (size_t)b * DIM * SLEN, out + qo, 0, 1);
    }
  }
}

// Round 8
// 277.788 us; speedup vs baseline: 1.2283x; 1.0599x over previous
//
#include <hip/hip_runtime.h>
#include <hip/hip_bf16.h>
#include <hip/hip_fp16.h>

#define DIM 768
#define SLEN 4096
#define BATCH 4
#define NTILES 528   // 128-granular causal tiles per batch (S layout)
#define NT256 136    // 256-granular causal tiles per batch (qk grid)
#define SPB ((size_t)NTILES * 16384)

typedef __attribute__((ext_vector_type(8))) short short8;
typedef __attribute__((ext_vector_type(4))) short short4v;
typedef __attribute__((ext_vector_type(4))) float f32x4;
typedef __attribute__((ext_vector_type(8))) _Float16 f16x8;

typedef __attribute__((address_space(1))) void gvoid;
typedef __attribute__((address_space(3))) void lvoid;

__device__ __forceinline__ void gl_lds16(const void* g, void* l) {
  __builtin_amdgcn_global_load_lds((gvoid*)g, (lvoid*)l, 16, 0, 0);
}

__device__ __forceinline__ unsigned short f2h(float x) {
  union { _Float16 h; unsigned short u; } c; c.h = (_Float16)x; return c.u;
}
__device__ __forceinline__ float h2f(unsigned short u) {
  union { _Float16 h; unsigned short u; } c; c.u = u; return (float)c.h;
}

union V8 { short8 v; unsigned short u[8]; };

// ---------------- kernel 1: x fp32 -> fp16 ----------------
__global__ __launch_bounds__(256) void convert_x_kernel(
    const float* __restrict__ x, unsigned short* __restrict__ xb) {
  size_t i = ((size_t)blockIdx.x * 256 + threadIdx.x) * 8;
  f32x4 a = *(const f32x4*)(x + i);
  f32x4 b = *(const f32x4*)(x + i + 4);
  V8 o;
#pragma unroll
  for (int j = 0; j < 4; ++j) { o.u[j] = f2h(a[j]); o.u[4 + j] = f2h(b[j]); }
  *(short8*)(xb + i) = o.v;
}

// ---------------- kernel 2: W [k][n] fp32 -> Wt [n][k] fp16 ----------------
__global__ __launch_bounds__(256) void transpose_w_kernel(
    const float* __restrict__ Wq, const float* __restrict__ Wk,
    const float* __restrict__ Wv, unsigned short* __restrict__ Wt) {
  __shared__ float Tl[32][33];
  const float* Wi = blockIdx.z == 0 ? Wq : (blockIdx.z == 1 ? Wk : Wv);
  unsigned short* Wo = Wt + (size_t)blockIdx.z * DIM * DIM;
  int k0 = blockIdx.x * 32, n0 = blockIdx.y * 32;
  int t = threadIdx.x;
  int r = t >> 3, c4 = (t & 7) * 4;
  f32x4 v = *(const f32x4*)(Wi + (size_t)(k0 + r) * DIM + n0 + c4);
#pragma unroll
  for (int j = 0; j < 4; ++j) Tl[r][c4 + j] = v[j];
  __syncthreads();
  short4v ov;
#pragma unroll
  for (int j = 0; j < 4; ++j) ov[j] = (short)f2h(Tl[c4 + j][r]);
  *(short4v*)(Wo + (size_t)(n0 + r) * DIM + k0 + c4) = ov;
}

// ============ 256x256 GEMM core, group-pipelined, 1 barrier per K-tile ============
// LDS: A buf p @ p*32768 (A0 +0, A1 +16384); B buf p @ 65536+p*32768.
// Within a K-tile all waves only READ the active buffer; stages write the other
// buffer -> no intra-tile barriers. Fragment reads issue in 4 groups (8/4/8/4
// ds_read_b128); each 16-MFMA cluster is gated by a counted lgkmcnt + a
// sched_barrier(0) (compiler hoists MFMA past inline-asm waits otherwise).
// Tile boundary: s_waitcnt vmcnt(0) (own stages landed) then s_barrier
// (cross-wave visibility; round-4 sync rule).

#define STAGE(src, row0, kb, ldsoff)                                              \
  {                                                                               \
    gl_lds16((src) + (size_t)((row0) + rA) * DIM + (kb) + cA,                     \
             ldsb + (ldsoff) + t * 16);                                           \
    gl_lds16((src) + (size_t)((row0) + 64 + rA) * DIM + (kb) + cA,                \
             ldsb + (ldsoff) + 8192 + t * 16);                                    \
  }

#define STAGEP(srcp, stride, ldsoff)                                              \
  {                                                                               \
    gl_lds16((srcp) + (size_t)rA * (stride) + cA, ldsb + (ldsoff) + t * 16);      \
    gl_lds16((srcp) + (size_t)(64 + rA) * (stride) + cA,                          \
             ldsb + (ldsoff) + 8192 + t * 16);                                    \
  }

#define RDA(dst, base, chb)                                                       \
  _Pragma("unroll") for (int j = 0; j < 4; ++j)                                   \
      dst[j] = __builtin_bit_cast(f16x8, *(const short8*)(ldsb + (base) +         \
               (j * 32 + arow) * 128 + (chb)));

#define RDB(dst, base, chb)                                                       \
  _Pragma("unroll") for (int n = 0; n < 4; ++n)                                   \
      dst[n] = __builtin_bit_cast(f16x8, *(const short8*)(ldsb + (base) +         \
               bh * 16384 + (brow + n * 16) * 128 + (chb)));

#define MFMA16(af, bf, FO)                                                        \
  __builtin_amdgcn_s_setprio(1);                                                  \
  _Pragma("unroll") for (int j = 0; j < 4; ++j)                                   \
    _Pragma("unroll") for (int n = 0; n < 4; ++n)                                 \
      acc[(FO) + j][n] = __builtin_amdgcn_mfma_f32_16x16x32_f16(                  \
          af[j], bf[n], acc[(FO) + j][n], 0, 0, 0);                               \
  __builtin_amdgcn_s_setprio(0);

#define LGKM(N)                                                                   \
  asm volatile("s_waitcnt lgkmcnt(" #N ")" ::: "memory");                         \
  __builtin_amdgcn_sched_barrier(0);

#define TILE_BODY(aBx, bBx, STGB, STGA)                                           \
  {                                                                               \
    f16x8 a0_[4], a1_[4], a2_[4], a3_[4], b0_[4], b2_[4];                         \
    RDA(a0_, (aBx), ch0);                                                         \
    RDB(b0_, (bBx), ch0);                                                         \
    RDA(a1_, (aBx) + 16384, ch0);                                                 \
    STGB;                                                                         \
    LGKM(4); MFMA16(a0_, b0_, 0);                                                 \
    RDA(a2_, (aBx), ch0 ^ 64);                                                    \
    RDB(b2_, (bBx), ch0 ^ 64);                                                    \
    STGA;                                                                         \
    LGKM(8); MFMA16(a1_, b0_, 4);                                                 \
    RDA(a3_, (aBx) + 16384, ch0 ^ 64);                                            \
    LGKM(4); MFMA16(a2_, b2_, 0);                                                 \
    LGKM(0); MFMA16(a3_, b2_, 4);                                                 \
    asm volatile("s_waitcnt vmcnt(0)" ::: "memory");                              \
    asm volatile("s_barrier" ::: "memory");                                       \
  }

// MODE 0: merged qkv. 1-D grid 576, XCD-swizzled. z<2: C=A(xb)xB(wt_z)^T -> Q/K.
//         z==2: Vt[e][s] = A(wt_v) x B(xb)^T (swapped roles, out ld=SLEN).
// MODE 1: causal qk 256-tiles (x XCD-swizzled per batch) -> packed-128 S scatter.
template <int MODE>
__global__ __launch_bounds__(512, 2) void gemm8_kernel(
    const unsigned short* __restrict__ Ag, const unsigned short* __restrict__ Bg,
    unsigned short* __restrict__ o0, unsigned short* __restrict__ o1,
    unsigned short* __restrict__ o2, size_t stAB, size_t stS) {
  __shared__ __align__(16) unsigned short lds[65536];  // 128 KiB
  char* ldsb = (char*)lds;
  const int t = threadIdx.x;
  const int lane = t & 63, w = t >> 6;
  const int l15 = lane & 15, lg = lane >> 4;
  const int wr = w >> 2, wc = w & 3;

  int m0, n0, qt = 0, kt = 0, z = 0;
  const unsigned short *A, *B;
  unsigned short* Co = nullptr;
  unsigned short* Sb = nullptr;
  if (MODE == 0) {
    const int o = blockIdx.x;
    const int oi = (o & 7) * 72 + (o >> 3);  // 576 = 8*72, bijective
    const int mt = oi / 9, sub = oi - mt * 9;
    const int ntile = sub / 3;
    z = sub - ntile * 3;
    if (z < 2) {
      m0 = mt * 256; n0 = ntile * 256;
      A = Ag; B = Bg + (size_t)z * DIM * DIM;
      Co = z == 0 ? o0 : o1;
    } else {
      m0 = ntile * 256; n0 = mt * 256;  // m: e-dim, n: s-dim
      A = Bg + (size_t)2 * DIM * DIM; B = Ag;
      Co = o2;
    }
  } else {
    const int i0 = blockIdx.x, b = blockIdx.y;
    const int i = (i0 & 7) * 17 + (i0 >> 3);  // 136 = 8*17, bijective
    qt = (int)((sqrtf(8.f * i + 1.f) - 1.f) * 0.5f);
    while ((qt + 1) * (qt + 2) / 2 <= i) ++qt;
    while (qt * (qt + 1) / 2 > i) --qt;
    kt = i - qt * (qt + 1) / 2;
    m0 = qt * 256; n0 = kt * 256;
    A = Ag + (size_t)b * stAB; B = Bg + (size_t)b * stAB;
    Sb = o0 + (size_t)b * stS;
  }

  const int rA = t >> 3;
  const int cA = (((t & 7) ^ ((t >> 3) & 7)) << 3);  // inverse-swizzled src chunk
  const int ch0 = ((lg ^ (l15 & 7)) << 4);           // swizzled ds_read chunk byte
  const int arow = wr * 16 + l15;
  const int bh = wc >> 1;
  const int brow = (wc & 1) * 64 + l15;

  f32x4 acc[8][4];
#pragma unroll
  for (int f = 0; f < 8; ++f)
#pragma unroll
    for (int n = 0; n < 4; ++n) acc[f][n] = f32x4{0.f, 0.f, 0.f, 0.f};

  // prologue: full tile 0 into buf0
  STAGE(A, m0, 0, 0);
  STAGE(A, m0 + 128, 0, 16384);
  STAGE(B, n0, 0, 65536);
  STAGE(B, n0 + 128, 0, 65536 + 16384);
  asm volatile("s_waitcnt vmcnt(0)" ::: "memory");
  asm volatile("s_barrier" ::: "memory");

  for (int tt = 0; tt < 12; ++tt) {
    const int bt = tt & 1;
    const int aB = bt * 32768;
    const int bB = 65536 + bt * 32768;
    const int aN = (1 - bt) * 32768;
    const int bN = 65536 + (1 - bt) * 32768;
    const int kb1 = (tt + 1 < 12 ? tt + 1 : 11) * 64;
    TILE_BODY(aB, bB,
              STAGE(B, n0, kb1, bN); STAGE(B, n0 + 128, kb1, bN + 16384),
              STAGE(A, m0, kb1, aN); STAGE(A, m0 + 128, kb1, aN + 16384));
  }

  if (MODE == 0) {
    if (z < 2) {
#pragma unroll
      for (int f = 0; f < 8; ++f) {
        const int row = m0 + f * 32 + wr * 16 + lg * 4;
#pragma unroll
        for (int n = 0; n < 4; ++n) {
          const int col = n0 + wc * 64 + n * 16 + l15;
#pragma unroll
          for (int ii = 0; ii < 4; ++ii)
            Co[(size_t)(row + ii) * DIM + col] = f2h(acc[f][n][ii]);
        }
      }
    } else {
      const int bb = n0 >> 12;
      unsigned short* O = Co + (size_t)bb * DIM * SLEN;
#pragma unroll
      for (int f = 0; f < 8; ++f) {
        const int row = m0 + f * 32 + wr * 16 + lg * 4;  // e
#pragma unroll
        for (int n = 0; n < 4; ++n) {
          const int sl = (n0 + wc * 64 + n * 16 + l15) & (SLEN - 1);
#pragma unroll
          for (int ii = 0; ii < 4; ++ii)
            O[(size_t)(row + ii) * SLEN + sl] = f2h(acc[f][n][ii]);
        }
      }
    }
  } else {
#pragma unroll
    for (int f = 0; f < 8; ++f) {
      const int rl = (f * 32 + wr * 16 + lg * 4) & 127;
      const int Q128 = qt * 2 + (f >= 4 ? 1 : 0);
      const int K128 = kt * 2 + (wc >> 1);
      if (K128 > Q128) continue;
      const size_t tb = (size_t)(Q128 * (Q128 + 1) / 2 + K128) * 16384;
#pragma unroll
      for (int n = 0; n < 4; ++n) {
        const int cl = ((wc & 1) * 64 + n * 16 + l15);
#pragma unroll
        for (int ii = 0; ii < 4; ++ii)
          Sb[tb + (size_t)(rl + ii) * 128 + cl] = f2h(acc[f][n][ii]);
      }
    }
  }
}

// ---------------- row softmax (in-place, causal mask, normalize) ----------------
__global__ __launch_bounds__(256) void softmax_kernel(
    unsigned short* __restrict__ S, size_t s_bstride) {
  __shared__ float redm[4], reds[4];
  const int r = blockIdx.x, b = blockIdx.y;
  unsigned short* Sb = S + (size_t)b * s_bstride;
  const int qt = r >> 7, rl = r & 127;
  const int ncols = (qt + 1) * 128;
  const size_t rowbase = (size_t)(qt * (qt + 1) / 2) * 16384 + (size_t)rl * 128;
  const int t = threadIdx.x, lane = t & 63, w = t >> 6;
  const int c0 = t * 16;
  const bool act = c0 < ncols;
  const float NEG = -3.0e38f;
  float sv[16];
  unsigned short* p = nullptr;
  if (act) {
    int ktile = c0 >> 7, cl = c0 & 127;
    p = Sb + rowbase + (size_t)ktile * 16384 + cl;
    V8 v0, v1; v0.v = *(const short8*)p; v1.v = *(const short8*)(p + 8);
#pragma unroll
    for (int j = 0; j < 8; ++j) {
      sv[j] = (c0 + j > r) ? NEG : h2f(v0.u[j]);
      sv[8 + j] = (c0 + 8 + j > r) ? NEG : h2f(v1.u[j]);
    }
  } else {
#pragma unroll
    for (int j = 0; j < 16; ++j) sv[j] = NEG;
  }
  float mx = NEG;
#pragma unroll
  for (int j = 0; j < 16; ++j) mx = fmaxf(mx, sv[j]);
#pragma unroll
  for (int d = 1; d < 64; d <<= 1) mx = fmaxf(mx, __shfl_xor(mx, d));
  if (lane == 0) redm[w] = mx;
  __syncthreads();
  mx = fmaxf(fmaxf(redm[0], redm[1]), fmaxf(redm[2], redm[3]));
  const float scl = 1.4426950408889634f / 27.712812921102035f;  // log2(e)/sqrt(768)
  float e[16], sm = 0.f;
#pragma unroll
  for (int j = 0; j < 16; ++j) { e[j] = exp2f((sv[j] - mx) * scl); sm += e[j]; }
#pragma unroll
  for (int d = 1; d < 64; d <<= 1) sm += __shfl_xor(sm, d);
  if (lane == 0) reds[w] = sm;
  __syncthreads();
  float inv = 1.0f / (reds[0] + reds[1] + reds[2] + reds[3]);
  if (act) {
    V8 o0, o1;
#pragma unroll
    for (int j = 0; j < 8; ++j) { o0.u[j] = f2h(e[j] * inv); o1.u[j] = f2h(e[8 + j] * inv); }
    *(short8*)p = o0.v;
    *(short8*)(p + 8) = o1.v;
  }
}

// ---------------- zero the 128x128 f16 scratch tile ----------------
__global__ __launch_bounds__(256) void zero_tile_kernel(unsigned short* __restrict__ z) {
  ((short8*)z)[blockIdx.x * 256 + threadIdx.x] = short8{0, 0, 0, 0, 0, 0, 0, 0};
}

// ---------------- PV: 256x256 group-pipelined, balanced split-K ----------------
__device__ const int pv_mt[24]  = {15,15,7,14,14,13,13,6,12,12,11,11,5,10,10,9,9,4,8,8,3,2,1,0};
__device__ const int pv_ks0[24] = {0,32,0,0,30,0,28,0,0,26,0,24,0,0,22,0,20,0,0,18,0,0,0,0};
__device__ const int pv_kl[24]  = {32,32,32,30,30,28,28,28,26,26,24,24,24,22,22,20,20,20,18,18,16,12,8,4};
__device__ const int pv_sec[24] = {0,1,0,0,1,0,1,0,0,1,0,1,0,0,1,0,1,0,0,1,0,0,0,0};

__global__ __launch_bounds__(512, 2) void pv256_kernel(
    const unsigned short* __restrict__ S, const unsigned short* __restrict__ Vt,
    const unsigned short* __restrict__ Zt, float* __restrict__ Out,
    float* __restrict__ Part) {
  __shared__ __align__(16) unsigned short lds[65536];
  char* ldsb = (char*)lds;
  const int t = threadIdx.x, lane = t & 63, w = t >> 6;
  const int l15 = lane & 15, lg = lane >> 4;
  const int wr = w >> 2, wc = w & 3;
  const int rank = blockIdx.x / 12, sub = blockIdx.x % 12;
  const int b = sub / 3, nt = sub % 3;
  const int mt = pv_mt[rank], ks0 = pv_ks0[rank], kl = pv_kl[rank];
  const int sec = pv_sec[rank];
  const int q0 = 2 * mt, q1 = 2 * mt + 1;
  const int kend = ks0 + kl;
  const unsigned short* Sbb = S + (size_t)b * SPB;
  const unsigned short* Vb = Vt + (size_t)b * DIM * SLEN + (size_t)(nt * 256) * SLEN;

  auto asrc = [&](int ks, int qh) -> const unsigned short* {
    const int K128 = ks >> 1;
    const unsigned short* base =
        (K128 <= qh) ? Sbb + (size_t)(qh * (qh + 1) / 2 + K128) * 16384 : Zt;
    return base + (ks & 1) * 64;
  };

  const int rA = t >> 3;
  const int cA = (((t & 7) ^ ((t >> 3) & 7)) << 3);
  const int ch0 = ((lg ^ (l15 & 7)) << 4);
  const int arow = wr * 16 + l15;
  const int bh = wc >> 1;
  const int brow = (wc & 1) * 64 + l15;

  f32x4 acc[8][4];
#pragma unroll
  for (int f = 0; f < 8; ++f)
#pragma unroll
    for (int n = 0; n < 4; ++n) acc[f][n] = f32x4{0.f, 0.f, 0.f, 0.f};

  // prologue: full tile ks0 into buf0
  STAGEP(asrc(ks0, q0), 128, 0);
  STAGEP(asrc(ks0, q1), 128, 16384);
  STAGEP(Vb + (size_t)ks0 * 64, SLEN, 65536);
  STAGEP(Vb + (size_t)128 * SLEN + (size_t)ks0 * 64, SLEN, 65536 + 16384);
  asm volatile("s_waitcnt vmcnt(0)" ::: "memory");
  asm volatile("s_barrier" ::: "memory");

  for (int it = 0; it < kl; ++it) {
    const int ts = ks0 + it;
    const int bt = it & 1;
    const int aB = bt * 32768;
    const int bB = 65536 + bt * 32768;
    const int aN = (1 - bt) * 32768;
    const int bN = 65536 + (1 - bt) * 32768;
    const int t1 = (ts + 1 < kend) ? ts + 1 : kend - 1;
    TILE_BODY(aB, bB,
              STAGEP(Vb + (size_t)t1 * 64, SLEN, bN);
              STAGEP(Vb + (size_t)128 * SLEN + (size_t)t1 * 64, SLEN, bN + 16384),
              STAGEP(asrc(t1, q0), 128, aN);
              STAGEP(asrc(t1, q1), 128, aN + 16384));
  }

  if (!sec) {
    float* Ob = Out + (size_t)b * SLEN * DIM + (size_t)(mt * 256) * DIM + nt * 256;
#pragma unroll
    for (int f = 0; f < 8; ++f) {
      const int rl = f * 32 + wr * 16 + lg * 4;
#pragma unroll
      for (int n = 0; n < 4; ++n) {
        const int cl = wc * 64 + n * 16 + l15;
#pragma unroll
        for (int ii = 0; ii < 4; ++ii)
          Ob[(size_t)(rl + ii) * DIM + cl] = acc[f][n][ii];
      }
    }
  } else {
    float* Pb = Part + (size_t)((b * 3 + nt) * 8 + (mt - 8)) * 65536;
#pragma unroll
    for (int f = 0; f < 8; ++f) {
      const int rl = f * 32 + wr * 16 + lg * 4;
#pragma unroll
      for (int n = 0; n < 4; ++n) {
        const int cl = wc * 64 + n * 16 + l15;
#pragma unroll
        for (int ii = 0; ii < 4; ++ii)
          Pb[(size_t)(rl + ii) * 256 + cl] = acc[f][n][ii];
      }
    }
  }
}

// ---------------- add secondary-segment partials into out ----------------
__global__ __launch_bounds__(256) void pv_reduce_kernel(
    const float* __restrict__ Part, float* __restrict__ Out) {
  const int bx = blockIdx.x;            // 0..6143
  const int p = bx >> 6;                // partial slot 0..95
  const int within = ((bx & 63) * 256 + threadIdx.x) * 4;
  const int mt = 8 + (p & 7);
  const int bnt = p >> 3, b = bnt / 3, nt = bnt % 3;
  const int r = within >> 8, c = within & 255;
  float* o = Out + (size_t)b * SLEN * DIM + (size_t)(mt * 256 + r) * DIM + nt * 256 + c;
  const f32x4 pv = *(const f32x4*)(Part + (size_t)p * 65536 + within);
  const f32x4 ov = *(const f32x4*)o;
  *(f32x4*)o = ov + pv;
}

// ---------------- fallback PV GEMM (packed P x Vt^T -> out fp32) ----------------
__global__ __launch_bounds__(256) void gemm_pv_kernel(
    const unsigned short* __restrict__ S, const unsigned short* __restrict__ Vt,
    float* __restrict__ Out, size_t s_bstride, int nb) {
  __shared__ __align__(16) unsigned short As[4096], Bs[4096];
  const int idx = blockIdx.x;
  const int qtr = idx / (6 * nb);
  const int rem = idx - qtr * 6 * nb;
  const int b = rem / 6, nt = rem % 6;
  const int qt = 31 - qtr;
  const unsigned short* Sb = S + (size_t)b * s_bstride + (size_t)(qt * (qt + 1) / 2) * 16384;
  const unsigned short* Vb = Vt + (size_t)b * DIM * SLEN + (size_t)(nt * 128) * SLEN;
  float* Ob = Out + (size_t)b * SLEN * DIM + (size_t)(qt * 128) * DIM + nt * 128;
  const int t = threadIdx.x, lane = t & 63, w = t >> 6;
  const int l15 = lane & 15, lg = lane >> 4;
  const int wm = w >> 1, wn = w & 1;
  f32x4 acc[4][4];
#pragma unroll
  for (int a = 0; a < 4; ++a)
#pragma unroll
    for (int b2 = 0; b2 < 4; ++b2) acc[a][b2] = f32x4{0.f, 0.f, 0.f, 0.f};
  const int c0 = t, c1 = t + 256;
  const int r0 = c0 >> 2, k80 = (c0 & 3) * 8;
  const int r1 = c1 >> 2, k81 = (c1 & 3) * 8;
  const int ksteps = (qt + 1) * 4;
  for (int ks = 0; ks < ksteps; ++ks) {
    const int kb = ks * 32;
    const size_t atile = (size_t)(kb >> 7) * 16384 + (size_t)(kb & 127);
    __syncthreads();
    gl_lds16(Sb + atile + (size_t)r0 * 128 + k80, As + (size_t)c0 * 8);
    gl_lds16(Sb + atile + (size_t)r1 * 128 + k81, As + (size_t)c1 * 8);
    gl_lds16(Vb + (size_t)r0 * SLEN + kb + k80, Bs + (size_t)c0 * 8);
    gl_lds16(Vb + (size_t)r1 * SLEN + kb + k81, Bs + (size_t)c1 * 8);
    __syncthreads();
    f16x8 a[4], bf[4];
#pragma unroll
    for (int mi = 0; mi < 4; ++mi)
      a[mi] = __builtin_bit_cast(f16x8, *(const short8*)(As + (wm * 64 + mi * 16 + l15) * 32 + lg * 8));
#pragma unroll
    for (int ni = 0; ni < 4; ++ni)
      bf[ni] = __builtin_bit_cast(f16x8, *(const short8*)(Bs + (wn * 64 + ni * 16 + l15) * 32 + lg * 8));
#pragma unroll
    for (int mi = 0; mi < 4; ++mi)
#pragma unroll
      for (int ni = 0; ni < 4; ++ni)
        acc[mi][ni] = __builtin_amdgcn_mfma_f32_16x16x32_f16(a[mi], bf[ni], acc[mi][ni], 0, 0, 0);
  }
#pragma unroll
  for (int mi = 0; mi < 4; ++mi)
#pragma unroll
    for (int ni = 0; ni < 4; ++ni)
#pragma unroll
      for (int ii = 0; ii < 4; ++ii) {
        int rl = wm * 64 + mi * 16 + lg * 4 + ii;
        int cl = wn * 64 + ni * 16 + l15;
        Ob[(size_t)rl * DIM + cl] = acc[mi][ni][ii];
      }
}

// ---------------- host launcher ----------------
extern "C" void kernel_launch(void* const* d_in, const int* in_sizes, int n_in,
                              void* d_out, int out_size, void* d_ws, size_t ws_size,
                              hipStream_t stream) {
  const float* x  = (const float*)d_in[0];
  const float* Wq = (const float*)d_in[1];
  const float* Wk = (const float*)d_in[2];
  const float* Wv = (const float*)d_in[3];
  float* out = (float*)d_out;

  const size_t n_x = (size_t)BATCH * SLEN * DIM;  // 12,582,912
  unsigned short* Q  = (unsigned short*)d_ws;
  unsigned short* K  = Q + n_x;
  unsigned short* Vt = K + n_x;
  unsigned short* xb = Vt + n_x;
  unsigned short* wt = xb + n_x;
  const size_t base_elems = 4 * n_x + (size_t)3 * DIM * DIM;  // 52,101,120
  const bool full = ws_size >= (base_elems + 4 * SPB) * 2;    // 173,408,256 B

  convert_x_kernel<<<dim3((unsigned)(n_x / 8 / 256)), 256, 0, stream>>>(x, xb);
  transpose_w_kernel<<<dim3(DIM / 32, DIM / 32, 3), 256, 0, stream>>>(Wq, Wk, Wv, wt);

  // merged QKV: Q,K row-major + V transposed, one 576-block dispatch
  gemm8_kernel<0><<<dim3(576), 512, 0, stream>>>(xb, wt, Q, K, Vt, 0, 0);

  if (full) {
    unsigned short* S = (unsigned short*)d_ws + base_elems;
    zero_tile_kernel<<<8, 256, 0, stream>>>(wt);  // wt dead; first 16384 -> zero tile
    gemm8_kernel<1><<<dim3(NT256, BATCH), 512, 0, stream>>>(
        Q, K, S, nullptr, nullptr, (size_t)SLEN * DIM, SPB);
    softmax_kernel<<<dim3(SLEN, BATCH), 256, 0, stream>>>(S, SPB);
    pv256_kernel<<<dim3(288), 512, 0, stream>>>(S, Vt, wt, out, (float*)xb);
    pv_reduce_kernel<<<dim3(6144), 256, 0, stream>>>((const float*)xb, out);
  } else {
    unsigned short* S = xb;  // overlay dead xb region (25.2 MB >= 17.3 MB)
    for (int b = 0; b < BATCH; ++b) {
      const size_t qo = (size_t)b * SLEN * DIM;
      gemm8_kernel<1><<<dim3(NT256, 1), 512, 0, stream>>>(
          Q + qo, K + qo, S, nullptr, nullptr, 0, 0);
      softmax_kernel<<<dim3(SLEN, 1), 256, 0, stream>>>(S, 0);
      gemm_pv_kernel<<<dim3(32 * 6), 256, 0, stream>>>(
          S, Vt + (size_t)b * DIM * SLEN, out + qo, 0, 1);
    }
  }
}